// Round 1
// baseline (2540.335 us; speedup 1.0000x reference)
//
#include <hip/hip_runtime.h>

#define N_NODES 24
#define N_EDGES 76
#define N_GRAPHS 8192
#define HID 128
#define NODE_F 16
#define EDGE_F 8
#define N_LAYERS 4
#define TOT_N (N_NODES * N_GRAPHS)   /* 196608 */
#define TOT_E (N_EDGES * N_GRAPHS)   /* 622592 */

// ---------------- node encoder: h = relu(x @ W_node + b_node) ----------------
__global__ __launch_bounds__(256) void k_node_enc(
    const float* __restrict__ x, const float* __restrict__ Wn,
    const float* __restrict__ bn, float* __restrict__ h)
{
    int idx = blockIdx.x * 256 + threadIdx.x;   // = node*128 + c
    int node = idx >> 7, c = idx & 127;
    const float* xr = x + node * NODE_F;
    float acc = bn[c];
#pragma unroll
    for (int k = 0; k < NODE_F; ++k) acc = fmaf(xr[k], Wn[k * HID + c], acc);
    h[idx] = fmaxf(acc, 0.f);
}

// ------- topology pattern (identical across graphs): CSR + norms from graph 0 -------
__global__ void k_pattern(const int* __restrict__ ei, int* __restrict__ poff,
                          int* __restrict__ prl, float* __restrict__ pnorm,
                          float* __restrict__ psn)
{
    __shared__ int cnt[N_NODES], off[N_NODES + 1], loc[N_NODES];
    __shared__ float dinv[N_NODES];
    int t = threadIdx.x;
    if (t < N_NODES) cnt[t] = 0;
    __syncthreads();
    if (t < N_EDGES) atomicAdd(&cnt[ei[TOT_E + t]], 1);   // in-degree by col
    __syncthreads();
    if (t == 0) {
        int s = 0;
        for (int n = 0; n < N_NODES; ++n) { off[n] = s; s += cnt[n]; }
        off[N_NODES] = s;
    }
    __syncthreads();
    if (t < N_NODES) {
        loc[t] = off[t];
        float deg = (float)(cnt[t] + 1);   // +1 self loop
        dinv[t] = rsqrtf(deg);
        psn[t]  = 1.f / deg;               // self-loop norm = dinv^2
    }
    __syncthreads();
    if (t < N_EDGES) {
        int r = ei[t], cc = ei[TOT_E + t];
        int p = atomicAdd(&loc[cc], 1);
        prl[p]   = r;                       // row local id (graph 0 ids are local)
        pnorm[p] = dinv[r] * dinv[cc];
    }
    if (t <= N_NODES) poff[t] = off[t];
}

// ---------------- fused GCN layer: h = relu(agg(hWc)*norm + bc + hWr + br) ----------------
struct LayerSmem {
    float W[2][HID * 132];     // [mat][c*132+k] transposed, pad 132 (b128 conflict-optimal)
    float ht[N_NODES * 132];   // h tile, overlaid by t = h@Wc after matmul
    int   poff[N_NODES + 1];
    int   prl[N_EDGES];
    float pnorm[N_EDGES];
    float psn[N_NODES];
};

__global__ __launch_bounds__(256, 1) void k_layer(
    float* __restrict__ h, const float* __restrict__ Wc,
    const float* __restrict__ bc, const float* __restrict__ Wr,
    const float* __restrict__ br,
    const int* __restrict__ poff_g, const int* __restrict__ prl_g,
    const float* __restrict__ pnorm_g, const float* __restrict__ psn_g,
    int graphs_per_block)
{
    __shared__ LayerSmem s;
    const int t = threadIdx.x;
    const int c = t & 127, half = t >> 7, nb = half * 12;

    // stage weights transposed into LDS (once per block, amortized over 32 graphs)
    for (int i = t; i < HID * HID; i += 256) {
        int k = i >> 7, cc = i & 127;
        s.W[0][cc * 132 + k] = Wc[i];
        s.W[1][cc * 132 + k] = Wr[i];
    }
    if (t <= N_NODES) s.poff[t] = poff_g[t];
    if (t < N_EDGES) { s.prl[t] = prl_g[t]; s.pnorm[t] = pnorm_g[t]; }
    if (t < N_NODES) s.psn[t] = psn_g[t];
    const float bcc = bc[c], brc = br[c];
    __syncthreads();

    const int g0 = blockIdx.x * graphs_per_block;
    // prefetch first graph's h tile into registers
    float4 pf[3];
    {
        const float4* src = (const float4*)(h + (size_t)g0 * (N_NODES * HID));
#pragma unroll
        for (int j = 0; j < 3; ++j) pf[j] = src[t + 256 * j];
    }

    for (int gi = 0; gi < graphs_per_block; ++gi) {
        const int g = g0 + gi;
        // write prefetched h into LDS
#pragma unroll
        for (int j = 0; j < 3; ++j) {
            int flat = (t + 256 * j) * 4;          // element index within tile
            int n = flat >> 7, k = flat & 127;
            *(float4*)&s.ht[n * 132 + k] = pf[j];
        }
        __syncthreads();

        // issue prefetch of next graph (latency hides under matmul)
        if (gi + 1 < graphs_per_block) {
            const float4* src = (const float4*)(h + (size_t)(g + 1) * (N_NODES * HID));
#pragma unroll
            for (int j = 0; j < 3; ++j) pf[j] = src[t + 256 * j];
        }

        // matmul: accT = (h @ Wc)[n][c], accR = (h @ Wr)[n][c], 12 nodes per thread
        float accT[12], accR[12];
#pragma unroll
        for (int j = 0; j < 12; ++j) { accT[j] = 0.f; accR[j] = 0.f; }
        const float* wcp = &s.W[0][c * 132];
        const float* wrp = &s.W[1][c * 132];
#pragma unroll 2
        for (int kb = 0; kb < 32; ++kb) {
            const int k = kb * 4;
            const float4 w0 = *(const float4*)(wcp + k);
            const float4 w1 = *(const float4*)(wrp + k);
#pragma unroll
            for (int j = 0; j < 12; ++j) {
                const float4 h4 = *(const float4*)&s.ht[(nb + j) * 132 + k];
                accT[j] = fmaf(h4.x, w0.x, accT[j]);
                accT[j] = fmaf(h4.y, w0.y, accT[j]);
                accT[j] = fmaf(h4.z, w0.z, accT[j]);
                accT[j] = fmaf(h4.w, w0.w, accT[j]);
                accR[j] = fmaf(h4.x, w1.x, accR[j]);
                accR[j] = fmaf(h4.y, w1.y, accR[j]);
                accR[j] = fmaf(h4.z, w1.z, accR[j]);
                accR[j] = fmaf(h4.w, w1.w, accR[j]);
            }
        }
        __syncthreads();              // all h reads done -> safe to overlay t
#pragma unroll
        for (int j = 0; j < 12; ++j) s.ht[(nb + j) * 132 + c] = accT[j];
        __syncthreads();

        // aggregate + bias + residual + relu, write back in place
        float* hout = h + (size_t)g * (N_NODES * HID);
#pragma unroll
        for (int j = 0; j < 12; ++j) {
            const int n = nb + j;
            float v = bcc + brc + accR[j] + s.psn[n] * accT[j];
            const int pe = s.poff[n + 1];
            for (int p = s.poff[n]; p < pe; ++p)
                v = fmaf(s.pnorm[p], s.ht[s.prl[p] * 132 + c], v);
            hout[n * HID + c] = fmaxf(v, 0.f);
        }
        __syncthreads();              // t reads done -> safe to overwrite ht next iter
    }
}

// ---------------- decoder (edge encoder fused in): one wave per edge ----------------
__global__ __launch_bounds__(256) void k_decoder(
    const float* __restrict__ h, const int* __restrict__ ei,
    const float* __restrict__ ea, const float* __restrict__ We,
    const float* __restrict__ be, const float* __restrict__ Wd,
    const float* __restrict__ bd, float* __restrict__ out)
{
    const int wv = threadIdx.x >> 6, lane = threadIdx.x & 63;
    const int e = blockIdx.x * 4 + wv;
    const int row = ei[e], col = ei[TOT_E + e];
    const int pos = e % N_EDGES;
    const float* eav = ea + (size_t)e * EDGE_F;
    float a[8];
#pragma unroll
    for (int f = 0; f < 8; ++f) a[f] = eav[f];
    float partial = 0.f;
#pragma unroll
    for (int u = 0; u < 2; ++u) {
        const int cc = lane + u * 64;
        float enc = be[cc] + We[(EDGE_F + pos) * HID + cc];
#pragma unroll
        for (int f = 0; f < 8; ++f) enc = fmaf(a[f], We[f * HID + cc], enc);
        enc = fmaxf(enc, 0.f);
        partial = fmaf(h[(size_t)row * HID + cc], Wd[cc], partial);
        partial = fmaf(h[(size_t)col * HID + cc], Wd[HID + cc], partial);
        partial = fmaf(enc, Wd[2 * HID + cc], partial);
    }
#pragma unroll
    for (int o = 32; o > 0; o >>= 1) partial += __shfl_xor(partial, o, 64);
    if (lane == 0) out[e] = partial + bd[0];
}

extern "C" void kernel_launch(void* const* d_in, const int* in_sizes, int n_in,
                              void* d_out, int out_size, void* d_ws, size_t ws_size,
                              hipStream_t stream) {
    const float* x   = (const float*)d_in[0];
    const int*   ei  = (const int*)d_in[1];   // [2][TOT_E]
    const float* ea  = (const float*)d_in[2];
    /* d_in[3] = batch, unused */
    const float* Wn  = (const float*)d_in[4];
    const float* bn  = (const float*)d_in[5];
    const float* We  = (const float*)d_in[6];
    const float* be  = (const float*)d_in[7];
    const float* Wcv = (const float*)d_in[8];
    const float* bcv = (const float*)d_in[9];
    const float* Wr  = (const float*)d_in[10];
    const float* br  = (const float*)d_in[11];
    const float* Wd  = (const float*)d_in[12];
    const float* bd  = (const float*)d_in[13];
    float* out = (float*)d_out;

    char* ws = (char*)d_ws;
    float* h = (float*)ws;                                    // [TOT_N][128]
    size_t hbytes = (size_t)TOT_N * HID * sizeof(float);      // ~100.7 MB
    int*   poff  = (int*)(ws + hbytes);
    int*   prl   = poff + 32;
    float* pnorm = (float*)(prl + 96);
    float* psn   = pnorm + 96;

    k_node_enc<<<TOT_N * HID / 256, 256, 0, stream>>>(x, Wn, bn, h);
    k_pattern<<<1, 128, 0, stream>>>(ei, poff, prl, pnorm, psn);
    const int GPB = N_GRAPHS / 256;   // 32 graphs per block, 256 blocks = 1/CU
    for (int l = 0; l < N_LAYERS; ++l)
        k_layer<<<256, 256, 0, stream>>>(h, Wcv + l * HID * HID, bcv + l * HID,
                                         Wr, br, poff, prl, pnorm, psn, GPB);
    k_decoder<<<TOT_E / 4, 256, 0, stream>>>(h, ei, ea, We, be, Wd, bd, out);
}

// Round 2
// 1654.362 us; speedup vs baseline: 1.5355x; 1.5355x over previous
//
#include <hip/hip_runtime.h>

#define N_NODES 24
#define N_EDGES 76
#define N_GRAPHS 8192
#define HID 128
#define NODE_F 16
#define EDGE_F 8
#define N_LAYERS 4
#define TOT_N (N_NODES * N_GRAPHS)   /* 196608 */
#define TOT_E (N_EDGES * N_GRAPHS)   /* 622592 */

// ---------------- node encoder: h = relu(x @ W_node + b_node) ----------------
__global__ __launch_bounds__(256) void k_node_enc(
    const float* __restrict__ x, const float* __restrict__ Wn,
    const float* __restrict__ bn, float* __restrict__ h)
{
    int idx = blockIdx.x * 256 + threadIdx.x;   // = node*128 + c
    int node = idx >> 7, c = idx & 127;
    const float* xr = x + node * NODE_F;
    float acc = bn[c];
#pragma unroll
    for (int k = 0; k < NODE_F; ++k) acc = fmaf(xr[k], Wn[k * HID + c], acc);
    h[idx] = fmaxf(acc, 0.f);
}

// ------- topology pattern (identical across graphs): CSR + norms from graph 0 -------
__global__ void k_pattern(const int* __restrict__ ei, int* __restrict__ poff,
                          int* __restrict__ prl, float* __restrict__ pnorm,
                          float* __restrict__ psn)
{
    __shared__ int cnt[N_NODES], off[N_NODES + 1], loc[N_NODES];
    __shared__ float dinv[N_NODES];
    int t = threadIdx.x;
    if (t < N_NODES) cnt[t] = 0;
    __syncthreads();
    if (t < N_EDGES) atomicAdd(&cnt[ei[TOT_E + t]], 1);   // in-degree by col
    __syncthreads();
    if (t == 0) {
        int s = 0;
        for (int n = 0; n < N_NODES; ++n) { off[n] = s; s += cnt[n]; }
        off[N_NODES] = s;
    }
    __syncthreads();
    if (t < N_NODES) {
        loc[t] = off[t];
        float deg = (float)(cnt[t] + 1);   // +1 self loop
        dinv[t] = rsqrtf(deg);
        psn[t]  = 1.f / deg;               // self-loop norm = dinv^2
    }
    __syncthreads();
    if (t < N_EDGES) {
        int r = ei[t], cc = ei[TOT_E + t];
        int p = atomicAdd(&loc[cc], 1);
        prl[p]   = r;                       // row local id (graph 0 ids are local)
        pnorm[p] = dinv[r] * dinv[cc];
    }
    if (t <= N_NODES) poff[t] = off[t];
}

// ---------------- fused GCN layer: h = relu(agg(hWc)*norm + bc + hWr + br) ----------------
struct LayerSmem {
    float W[2][HID * 132];     // [mat][c*132+k] transposed, pad 132 (b128 conflict-optimal)
    float ht[N_NODES * 132];   // h tile, overlaid by t = h@Wc after matmul
    int   poff[N_NODES + 1];
    int   prl[N_EDGES];
    float pnorm[N_EDGES];
    float psn[N_NODES];
};

// 768 threads = 12 waves/CU (3/SIMD): latency hiding that 256 threads (1 wave/SIMD)
// could not provide. Each thread: 1 column c, 4 nodes. grp = t>>7 is wave-uniform,
// so all h-tile LDS reads are wave-broadcasts (conflict-free); only the W reads are
// strided (pad 132 = conflict-optimal for b128).
__global__ __launch_bounds__(768, 1) void k_layer(
    float* __restrict__ h, const float* __restrict__ Wc,
    const float* __restrict__ bc, const float* __restrict__ Wr,
    const float* __restrict__ br,
    const int* __restrict__ poff_g, const int* __restrict__ prl_g,
    const float* __restrict__ pnorm_g, const float* __restrict__ psn_g,
    int graphs_per_block)
{
    __shared__ LayerSmem s;
    const int t = threadIdx.x;
    const int c = t & 127, grp = t >> 7, nb = grp * 4;   // grp in [0,6)

    // stage weights transposed into LDS (once per block, amortized over 32 graphs)
    for (int i = t; i < HID * HID; i += 768) {
        int k = i >> 7, cc = i & 127;
        s.W[0][cc * 132 + k] = Wc[i];
        s.W[1][cc * 132 + k] = Wr[i];
    }
    if (t <= N_NODES) s.poff[t] = poff_g[t];
    if (t < N_EDGES) { s.prl[t] = prl_g[t]; s.pnorm[t] = pnorm_g[t]; }
    if (t < N_NODES) s.psn[t] = psn_g[t];
    const float bcc = bc[c], brc = br[c];
    __syncthreads();

    const int g0 = blockIdx.x * graphs_per_block;
    // prefetch first graph's h tile: exactly one float4 per thread (768*4 = 3072 elems)
    float4 pf;
    pf = ((const float4*)(h + (size_t)g0 * (N_NODES * HID)))[t];

    for (int gi = 0; gi < graphs_per_block; ++gi) {
        const int g = g0 + gi;
        // write prefetched h into LDS: element t*4 -> node t>>5, k (t*4)&127
        {
            int n = t >> 5, k = (t * 4) & 127;
            *(float4*)&s.ht[n * 132 + k] = pf;
        }
        __syncthreads();

        // issue prefetch of next graph (latency hides under matmul)
        if (gi + 1 < graphs_per_block)
            pf = ((const float4*)(h + (size_t)(g + 1) * (N_NODES * HID)))[t];

        // matmul: accT = (h @ Wc)[n][c], accR = (h @ Wr)[n][c], 4 nodes per thread
        float accT[4], accR[4];
#pragma unroll
        for (int j = 0; j < 4; ++j) { accT[j] = 0.f; accR[j] = 0.f; }
        const float* wcp = &s.W[0][c * 132];
        const float* wrp = &s.W[1][c * 132];
#pragma unroll 4
        for (int kb = 0; kb < 32; ++kb) {
            const int k = kb * 4;
            const float4 w0 = *(const float4*)(wcp + k);
            const float4 w1 = *(const float4*)(wrp + k);
#pragma unroll
            for (int j = 0; j < 4; ++j) {
                const float4 h4 = *(const float4*)&s.ht[(nb + j) * 132 + k];
                accT[j] = fmaf(h4.x, w0.x, accT[j]);
                accT[j] = fmaf(h4.y, w0.y, accT[j]);
                accT[j] = fmaf(h4.z, w0.z, accT[j]);
                accT[j] = fmaf(h4.w, w0.w, accT[j]);
                accR[j] = fmaf(h4.x, w1.x, accR[j]);
                accR[j] = fmaf(h4.y, w1.y, accR[j]);
                accR[j] = fmaf(h4.z, w1.z, accR[j]);
                accR[j] = fmaf(h4.w, w1.w, accR[j]);
            }
        }
        __syncthreads();              // all h reads done -> safe to overlay t
#pragma unroll
        for (int j = 0; j < 4; ++j) s.ht[(nb + j) * 132 + c] = accT[j];
        __syncthreads();

        // aggregate + bias + residual + relu, write back in place
        float* hout = h + (size_t)g * (N_NODES * HID);
#pragma unroll
        for (int j = 0; j < 4; ++j) {
            const int n = nb + j;
            float v = bcc + brc + accR[j] + s.psn[n] * accT[j];
            const int pe = s.poff[n + 1];
            for (int p = s.poff[n]; p < pe; ++p)
                v = fmaf(s.pnorm[p], s.ht[s.prl[p] * 132 + c], v);
            hout[n * HID + c] = fmaxf(v, 0.f);
        }
        __syncthreads();              // t reads done -> safe to overwrite ht next iter
    }
}

// ---------------- decoder (edge encoder fused in): one wave per edge ----------------
__global__ __launch_bounds__(256) void k_decoder(
    const float* __restrict__ h, const int* __restrict__ ei,
    const float* __restrict__ ea, const float* __restrict__ We,
    const float* __restrict__ be, const float* __restrict__ Wd,
    const float* __restrict__ bd, float* __restrict__ out)
{
    const int wv = threadIdx.x >> 6, lane = threadIdx.x & 63;
    const int e = blockIdx.x * 4 + wv;
    const int row = ei[e], col = ei[TOT_E + e];
    const int pos = e % N_EDGES;
    const float* eav = ea + (size_t)e * EDGE_F;
    float a[8];
#pragma unroll
    for (int f = 0; f < 8; ++f) a[f] = eav[f];
    float partial = 0.f;
#pragma unroll
    for (int u = 0; u < 2; ++u) {
        const int cc = lane + u * 64;
        float enc = be[cc] + We[(EDGE_F + pos) * HID + cc];
#pragma unroll
        for (int f = 0; f < 8; ++f) enc = fmaf(a[f], We[f * HID + cc], enc);
        enc = fmaxf(enc, 0.f);
        partial = fmaf(h[(size_t)row * HID + cc], Wd[cc], partial);
        partial = fmaf(h[(size_t)col * HID + cc], Wd[HID + cc], partial);
        partial = fmaf(enc, Wd[2 * HID + cc], partial);
    }
#pragma unroll
    for (int o = 32; o > 0; o >>= 1) partial += __shfl_xor(partial, o, 64);
    if (lane == 0) out[e] = partial + bd[0];
}

extern "C" void kernel_launch(void* const* d_in, const int* in_sizes, int n_in,
                              void* d_out, int out_size, void* d_ws, size_t ws_size,
                              hipStream_t stream) {
    const float* x   = (const float*)d_in[0];
    const int*   ei  = (const int*)d_in[1];   // [2][TOT_E]
    const float* ea  = (const float*)d_in[2];
    /* d_in[3] = batch, unused */
    const float* Wn  = (const float*)d_in[4];
    const float* bn  = (const float*)d_in[5];
    const float* We  = (const float*)d_in[6];
    const float* be  = (const float*)d_in[7];
    const float* Wcv = (const float*)d_in[8];
    const float* bcv = (const float*)d_in[9];
    const float* Wr  = (const float*)d_in[10];
    const float* br  = (const float*)d_in[11];
    const float* Wd  = (const float*)d_in[12];
    const float* bd  = (const float*)d_in[13];
    float* out = (float*)d_out;

    char* ws = (char*)d_ws;
    float* h = (float*)ws;                                    // [TOT_N][128]
    size_t hbytes = (size_t)TOT_N * HID * sizeof(float);      // ~100.7 MB
    int*   poff  = (int*)(ws + hbytes);
    int*   prl   = poff + 32;
    float* pnorm = (float*)(prl + 96);
    float* psn   = pnorm + 96;

    k_node_enc<<<TOT_N * HID / 256, 256, 0, stream>>>(x, Wn, bn, h);
    k_pattern<<<1, 128, 0, stream>>>(ei, poff, prl, pnorm, psn);
    const int GPB = N_GRAPHS / 256;   // 32 graphs per block, 256 blocks = 1/CU
    for (int l = 0; l < N_LAYERS; ++l)
        k_layer<<<256, 768, 0, stream>>>(h, Wcv + l * HID * HID, bcv + l * HID,
                                         Wr, br, poff, prl, pnorm, psn, GPB);
    k_decoder<<<TOT_E / 4, 256, 0, stream>>>(h, ei, ea, We, be, Wd, bd, out);
}

// Round 3
// 880.779 us; speedup vs baseline: 2.8842x; 1.8783x over previous
//
#include <hip/hip_runtime.h>

typedef short bf16x8 __attribute__((ext_vector_type(8)));
typedef float f32x4  __attribute__((ext_vector_type(4)));

#define N_NODES 24
#define N_EDGES 76
#define N_GRAPHS 8192
#define HID 128
#define NODE_F 16
#define EDGE_F 8
#define N_LAYERS 4
#define TOT_N (N_NODES * N_GRAPHS)   /* 196608 */
#define TOT_E (N_EDGES * N_GRAPHS)   /* 622592 */
#define ST 136        /* bf16 h-plane stride: 272 B rows, 16B-aligned, min-conflict */
#define TST 132       /* fp32 t-tile stride: bank = (4*row+col)%32, spread */

// ---------------- node encoder: h = relu(x @ W_node + b_node) ----------------
__global__ __launch_bounds__(256) void k_node_enc(
    const float* __restrict__ x, const float* __restrict__ Wn,
    const float* __restrict__ bn, float* __restrict__ h)
{
    int idx = blockIdx.x * 256 + threadIdx.x;   // = node*128 + c
    int node = idx >> 7, c = idx & 127;
    const float* xr = x + node * NODE_F;
    float acc = bn[c];
#pragma unroll
    for (int k = 0; k < NODE_F; ++k) acc = fmaf(xr[k], Wn[k * HID + c], acc);
    h[idx] = fmaxf(acc, 0.f);
}

// ------- topology pattern (identical across graphs): CSR + norms from graph 0 -------
__global__ void k_pattern(const int* __restrict__ ei, int* __restrict__ poff,
                          int* __restrict__ prl, float* __restrict__ pnorm,
                          float* __restrict__ psn)
{
    __shared__ int cnt[N_NODES], off[N_NODES + 1], loc[N_NODES];
    __shared__ float dinv[N_NODES];
    int t = threadIdx.x;
    if (t < N_NODES) cnt[t] = 0;
    __syncthreads();
    if (t < N_EDGES) atomicAdd(&cnt[ei[TOT_E + t]], 1);   // in-degree by col
    __syncthreads();
    if (t == 0) {
        int s = 0;
        for (int n = 0; n < N_NODES; ++n) { off[n] = s; s += cnt[n]; }
        off[N_NODES] = s;
    }
    __syncthreads();
    if (t < N_NODES) {
        loc[t] = off[t];
        float deg = (float)(cnt[t] + 1);   // +1 self loop
        dinv[t] = rsqrtf(deg);
        psn[t]  = 1.f / deg;               // self-loop norm = dinv^2
    }
    __syncthreads();
    if (t < N_EDGES) {
        int r = ei[t], cc = ei[TOT_E + t];
        int p = atomicAdd(&loc[cc], 1);
        prl[p]   = r;
        pnorm[p] = dinv[r] * dinv[cc];
    }
    if (t <= N_NODES) poff[t] = off[t];
}

// ------- W prep: transpose to [c][k] and split fp32 -> bf16 hi/lo planes -------
// mats 0..3 = W_conv[l], mat 4 = W_res. Truncation split: hi=trunc16(x),
// lo=trunc16(x-hi) -> hi+lo represents x to ~2^-14 rel.
__global__ __launch_bounds__(256) void k_wprep(
    const float* __restrict__ Wcv, const float* __restrict__ Wr,
    unsigned short* __restrict__ whi, unsigned short* __restrict__ wlo)
{
    int idx = blockIdx.x * 256 + threadIdx.x;    // [0, 5*16384)
    int m = idx >> 14, rem = idx & 16383;
    int k = rem >> 7, c = rem & 127;
    const float* src = (m < 4) ? (Wcv + m * 16384) : Wr;
    float x = src[k * HID + c];
    unsigned int u = __float_as_uint(x);
    unsigned short hi = (unsigned short)(u >> 16);
    float hf = __uint_as_float(u & 0xFFFF0000u);
    unsigned short lo = (unsigned short)(__float_as_uint(x - hf) >> 16);
    whi[m * 16384 + c * HID + k] = hi;
    wlo[m * 16384 + c * HID + k] = lo;
}

// ---------------- fused MFMA GCN layer ----------------
// 512 thr = 8 waves: wave w -> col-group cg=w&3 (32 cols), row-group rg=w>>2 (48 rows).
// Chunk = 4 graphs (M=96). W frags in registers (loaded once), h hi/lo planes in LDS,
// t = h@Wc written to LDS for CSR gather; r = h@Wr stays in accumulators.
struct LSmem {
    union {
        unsigned short planes[2][96 * ST];   // hi, lo bf16 h planes (52224 B)
        float tt[96 * TST];                  // conv result tile    (50688 B)
    } u;
    int poff[N_NODES + 1];
    int prl[N_EDGES];
    float pnorm[N_EDGES];
    float psn[N_NODES];
};

__global__ __launch_bounds__(512, 2) void k_layer(
    float* __restrict__ h,
    const unsigned short* __restrict__ whi, const unsigned short* __restrict__ wlo,
    int lmat, const float* __restrict__ bc, const float* __restrict__ br,
    const int* __restrict__ poff_g, const int* __restrict__ prl_g,
    const float* __restrict__ pnorm_g, const float* __restrict__ psn_g)
{
    __shared__ LSmem s;
    const int t = threadIdx.x;
    const int w = t >> 6, l = t & 63;
    const int cg = w & 3, rg = w >> 2;
    const int lr = l & 15, lq = l >> 4;

    if (t <= N_NODES) s.poff[t] = poff_g[t];
    if (t < N_EDGES) { s.prl[t] = prl_g[t]; s.pnorm[t] = pnorm_g[t]; }
    if (t < N_NODES) s.psn[t] = psn_g[t];

    // ---- W fragments into registers: [mat(c/r)][comp(hi/lo)][nt][ks] = 128 VGPR ----
    bf16x8 Wf[2][2][2][4];
#pragma unroll
    for (int mat = 0; mat < 2; ++mat) {
        const int mi = (mat == 0) ? lmat : 4;
#pragma unroll
        for (int nt = 0; nt < 2; ++nt) {
            const int col = 32 * cg + 16 * nt + lr;
#pragma unroll
            for (int ks = 0; ks < 4; ++ks) {
                const int off = mi * 16384 + col * HID + 32 * ks + 8 * lq;
                Wf[mat][0][nt][ks] = *(const bf16x8*)(whi + off);
                Wf[mat][1][nt][ks] = *(const bf16x8*)(wlo + off);
            }
        }
    }
    const int colA = 32 * cg + lr;
    const float bsum0 = bc[colA] + br[colA];
    const float bsum1 = bc[colA + 16] + br[colA + 16];
    __syncthreads();

    const long long blkrow0 = (long long)blockIdx.x * 32 * N_NODES;  // 32 graphs/block
    float4 pf[6];
    {
        const float4* hsrc = (const float4*)(h + blkrow0 * HID);
#pragma unroll
        for (int i = 0; i < 6; ++i) pf[i] = hsrc[t + 512 * i];
    }

    for (int ci = 0; ci < 8; ++ci) {
        // ---- stage h -> bf16 hi/lo planes ----
#pragma unroll
        for (int i = 0; i < 6; ++i) {
            const int e = (t + 512 * i) * 4;       // elem in 96x128 chunk
            const int row = e >> 7, k = e & 127;
            float xs[4] = {pf[i].x, pf[i].y, pf[i].z, pf[i].w};
            unsigned short hs[4], ls[4];
#pragma unroll
            for (int j = 0; j < 4; ++j) {
                unsigned int u = __float_as_uint(xs[j]);
                hs[j] = (unsigned short)(u >> 16);
                float hf = __uint_as_float(u & 0xFFFF0000u);
                ls[j] = (unsigned short)(__float_as_uint(xs[j] - hf) >> 16);
            }
            *(ushort4*)&s.u.planes[0][row * ST + k] = make_ushort4(hs[0], hs[1], hs[2], hs[3]);
            *(ushort4*)&s.u.planes[1][row * ST + k] = make_ushort4(ls[0], ls[1], ls[2], ls[3]);
        }
        __syncthreads();

        // prefetch next chunk's h (hides HBM latency under MFMA)
        if (ci < 7) {
            const float4* nsrc = (const float4*)(h + (blkrow0 + (ci + 1) * 96) * HID);
#pragma unroll
            for (int i = 0; i < 6; ++i) pf[i] = nsrc[t + 512 * i];
        }

        // ---- MFMA: accT = h@Wc, accR = h@Wr (3-pass split-bf16) ----
        f32x4 accT[3][2], accR[3][2];
#pragma unroll
        for (int mt = 0; mt < 3; ++mt)
#pragma unroll
            for (int nt = 0; nt < 2; ++nt) {
                accT[mt][nt] = (f32x4){0.f, 0.f, 0.f, 0.f};
                accR[mt][nt] = (f32x4){0.f, 0.f, 0.f, 0.f};
            }
#pragma unroll
        for (int ks = 0; ks < 4; ++ks) {
#pragma unroll
            for (int mt = 0; mt < 3; ++mt) {
                const int row = 48 * rg + 16 * mt + lr;
                const int koff = 32 * ks + 8 * lq;
                const bf16x8 ahi = *(const bf16x8*)&s.u.planes[0][row * ST + koff];
                const bf16x8 alo = *(const bf16x8*)&s.u.planes[1][row * ST + koff];
#pragma unroll
                for (int nt = 0; nt < 2; ++nt) {
                    accT[mt][nt] = __builtin_amdgcn_mfma_f32_16x16x32_bf16(ahi, Wf[0][0][nt][ks], accT[mt][nt], 0, 0, 0);
                    accT[mt][nt] = __builtin_amdgcn_mfma_f32_16x16x32_bf16(alo, Wf[0][0][nt][ks], accT[mt][nt], 0, 0, 0);
                    accT[mt][nt] = __builtin_amdgcn_mfma_f32_16x16x32_bf16(ahi, Wf[0][1][nt][ks], accT[mt][nt], 0, 0, 0);
                    accR[mt][nt] = __builtin_amdgcn_mfma_f32_16x16x32_bf16(ahi, Wf[1][0][nt][ks], accR[mt][nt], 0, 0, 0);
                    accR[mt][nt] = __builtin_amdgcn_mfma_f32_16x16x32_bf16(alo, Wf[1][0][nt][ks], accR[mt][nt], 0, 0, 0);
                    accR[mt][nt] = __builtin_amdgcn_mfma_f32_16x16x32_bf16(ahi, Wf[1][1][nt][ks], accR[mt][nt], 0, 0, 0);
                }
            }
        }
        __syncthreads();   // all h-plane reads done -> overlay tt

        // ---- write conv tile to LDS (C/D layout: col=lr, row=4*lq+j) ----
#pragma unroll
        for (int mt = 0; mt < 3; ++mt)
#pragma unroll
            for (int nt = 0; nt < 2; ++nt)
#pragma unroll
                for (int j = 0; j < 4; ++j) {
                    const int row = 48 * rg + 16 * mt + 4 * lq + j;
                    const int col = 32 * cg + 16 * nt + lr;
                    s.u.tt[row * TST + col] = accT[mt][nt][j];
                }
        __syncthreads();

        // ---- aggregate + bias + residual + relu -> global (in place) ----
        float* hdst = h + (blkrow0 + ci * 96) * HID;
#pragma unroll
        for (int mt = 0; mt < 3; ++mt)
#pragma unroll
            for (int nt = 0; nt < 2; ++nt)
#pragma unroll
                for (int j = 0; j < 4; ++j) {
                    const int r48 = 16 * mt + 4 * lq + j;         // [0,48)
                    const int gl2 = (r48 >= 24) ? 1 : 0;
                    const int nn = r48 - 24 * gl2;
                    const int gbase = (2 * rg + gl2) * 24;
                    const int col = 32 * cg + 16 * nt + lr;
                    float v = (nt ? bsum1 : bsum0) + accR[mt][nt][j]
                              + s.psn[nn] * accT[mt][nt][j];
                    const int pe = s.poff[nn + 1];
                    for (int p = s.poff[nn]; p < pe; ++p)
                        v = fmaf(s.pnorm[p], s.u.tt[(gbase + s.prl[p]) * TST + col], v);
                    hdst[(gbase + nn) * HID + col] = fmaxf(v, 0.f);
                }
        __syncthreads();   // tt reads done before next chunk's plane writes
    }
}

// ---------------- decoder (edge encoder fused in): one wave per edge ----------------
__global__ __launch_bounds__(256) void k_decoder(
    const float* __restrict__ h, const int* __restrict__ ei,
    const float* __restrict__ ea, const float* __restrict__ We,
    const float* __restrict__ be, const float* __restrict__ Wd,
    const float* __restrict__ bd, float* __restrict__ out)
{
    const int wv = threadIdx.x >> 6, lane = threadIdx.x & 63;
    const int e = blockIdx.x * 4 + wv;
    const int row = ei[e], col = ei[TOT_E + e];
    const int pos = e % N_EDGES;
    const float* eav = ea + (size_t)e * EDGE_F;
    float a[8];
#pragma unroll
    for (int f = 0; f < 8; ++f) a[f] = eav[f];
    float partial = 0.f;
#pragma unroll
    for (int u = 0; u < 2; ++u) {
        const int cc = lane + u * 64;
        float enc = be[cc] + We[(EDGE_F + pos) * HID + cc];
#pragma unroll
        for (int f = 0; f < 8; ++f) enc = fmaf(a[f], We[f * HID + cc], enc);
        enc = fmaxf(enc, 0.f);
        partial = fmaf(h[(size_t)row * HID + cc], Wd[cc], partial);
        partial = fmaf(h[(size_t)col * HID + cc], Wd[HID + cc], partial);
        partial = fmaf(enc, Wd[2 * HID + cc], partial);
    }
#pragma unroll
    for (int o = 32; o > 0; o >>= 1) partial += __shfl_xor(partial, o, 64);
    if (lane == 0) out[e] = partial + bd[0];
}

extern "C" void kernel_launch(void* const* d_in, const int* in_sizes, int n_in,
                              void* d_out, int out_size, void* d_ws, size_t ws_size,
                              hipStream_t stream) {
    const float* x   = (const float*)d_in[0];
    const int*   ei  = (const int*)d_in[1];   // [2][TOT_E]
    const float* ea  = (const float*)d_in[2];
    /* d_in[3] = batch, unused */
    const float* Wn  = (const float*)d_in[4];
    const float* bn  = (const float*)d_in[5];
    const float* We  = (const float*)d_in[6];
    const float* be  = (const float*)d_in[7];
    const float* Wcv = (const float*)d_in[8];
    const float* bcv = (const float*)d_in[9];
    const float* Wr  = (const float*)d_in[10];
    const float* br  = (const float*)d_in[11];
    const float* Wd  = (const float*)d_in[12];
    const float* bd  = (const float*)d_in[13];
    float* out = (float*)d_out;

    char* ws = (char*)d_ws;
    float* h = (float*)ws;                                    // [TOT_N][128] fp32
    size_t hbytes = (size_t)TOT_N * HID * sizeof(float);      // ~100.7 MB
    unsigned short* whi = (unsigned short*)(ws + hbytes);     // 5*16384 bf16
    unsigned short* wlo = whi + 5 * 16384;
    int*   poff  = (int*)(wlo + 5 * 16384);
    int*   prl   = poff + 32;
    float* pnorm = (float*)(prl + 96);
    float* psn   = pnorm + 96;

    k_node_enc<<<TOT_N * HID / 256, 256, 0, stream>>>(x, Wn, bn, h);
    k_pattern<<<1, 128, 0, stream>>>(ei, poff, prl, pnorm, psn);
    k_wprep<<<5 * 16384 / 256, 256, 0, stream>>>(Wcv, Wr, whi, wlo);
    for (int l = 0; l < N_LAYERS; ++l)
        k_layer<<<256, 512, 0, stream>>>(h, whi, wlo, l, bcv + l * HID, br,
                                         poff, prl, pnorm, psn);
    k_decoder<<<TOT_E / 4, 256, 0, stream>>>(h, ei, ea, We, be, Wd, bd, out);
}

// Round 4
// 759.565 us; speedup vs baseline: 3.3445x; 1.1596x over previous
//
#include <hip/hip_runtime.h>

typedef short bf16x8 __attribute__((ext_vector_type(8)));
typedef float f32x4  __attribute__((ext_vector_type(4)));

#define N_NODES 24
#define N_EDGES 76
#define N_GRAPHS 8192
#define HID 128
#define NODE_F 16
#define EDGE_F 8
#define N_LAYERS 4
#define TOT_N (N_NODES * N_GRAPHS)   /* 196608 */
#define TOT_E (N_EDGES * N_GRAPHS)   /* 622592 */
#define ST 136        /* bf16 h-plane stride (ushorts): 272B rows, 2-way max on b128 */
#define TST 133       /* fp32 t-tile stride: 24-row CSR gather spreads banks (24*133%32=24) */
#define HFST 132      /* fp32 final-h tile stride */

// ---------------- node encoder: h = relu(x @ W_node + b_node) ----------------
__global__ __launch_bounds__(256) void k_node_enc(
    const float* __restrict__ x, const float* __restrict__ Wn,
    const float* __restrict__ bn, float* __restrict__ h)
{
    int idx = blockIdx.x * 256 + threadIdx.x;   // = node*128 + c
    int node = idx >> 7, c = idx & 127;
    const float* xr = x + node * NODE_F;
    float acc = bn[c];
#pragma unroll
    for (int k = 0; k < NODE_F; ++k) acc = fmaf(xr[k], Wn[k * HID + c], acc);
    h[idx] = fmaxf(acc, 0.f);
}

// ------- topology pattern (identical across graphs): CSR + norms from graph 0 -------
__global__ void k_pattern(const int* __restrict__ ei, int* __restrict__ poff,
                          int* __restrict__ prl, float* __restrict__ pnorm,
                          float* __restrict__ psn)
{
    __shared__ int cnt[N_NODES], off[N_NODES + 1], loc[N_NODES];
    __shared__ float dinv[N_NODES];
    int t = threadIdx.x;
    if (t < N_NODES) cnt[t] = 0;
    __syncthreads();
    if (t < N_EDGES) atomicAdd(&cnt[ei[TOT_E + t]], 1);   // in-degree by col
    __syncthreads();
    if (t == 0) {
        int s = 0;
        for (int n = 0; n < N_NODES; ++n) { off[n] = s; s += cnt[n]; }
        off[N_NODES] = s;
    }
    __syncthreads();
    if (t < N_NODES) {
        loc[t] = off[t];
        float deg = (float)(cnt[t] + 1);   // +1 self loop
        dinv[t] = rsqrtf(deg);
        psn[t]  = 1.f / deg;               // self-loop norm = dinv^2
    }
    __syncthreads();
    if (t < N_EDGES) {
        int r = ei[t], cc = ei[TOT_E + t];
        int p = atomicAdd(&loc[cc], 1);
        prl[p]   = r;
        pnorm[p] = dinv[r] * dinv[cc];
    }
    if (t <= N_NODES) poff[t] = off[t];
}

// ------- W prep: transpose to [c][k] and split fp32 -> bf16 hi/lo planes -------
__global__ __launch_bounds__(256) void k_wprep(
    const float* __restrict__ Wcv, const float* __restrict__ Wr,
    unsigned short* __restrict__ whi, unsigned short* __restrict__ wlo)
{
    int idx = blockIdx.x * 256 + threadIdx.x;    // [0, 5*16384)
    int m = idx >> 14, rem = idx & 16383;
    int k = rem >> 7, c = rem & 127;
    const float* src = (m < 4) ? (Wcv + m * 16384) : Wr;
    float x = src[k * HID + c];
    unsigned int u = __float_as_uint(x);
    unsigned short hi = (unsigned short)(u >> 16);
    float hf = __uint_as_float(u & 0xFFFF0000u);
    unsigned short lo = (unsigned short)(__float_as_uint(x - hf) >> 16);
    whi[m * 16384 + c * HID + k] = hi;
    wlo[m * 16384 + c * HID + k] = lo;
}

// ---------------- fused MFMA GCN layer (+optional fused decoder) ----------------
// 1024 thr = 16 waves: wave w -> cg=w&7 (16 cols), rg=w>>3 (48 rows).
// Wf = 64 VGPR, acc = 24, pf = 12 -> fits 128-VGPR cap => 4 waves/SIMD.
struct SmemMid {
    union {
        unsigned short planes[2][96 * ST];   // hi, lo bf16 h planes (52224 B)
        float tt[96 * TST];                  // conv result tile (51072 B)
    } u;
    int poff[N_NODES + 1];
    int prl[N_EDGES];
    float pnorm[N_EDGES];
    float psn[N_NODES];
};
struct SmemDec { SmemMid m; float hf[96 * HFST]; };

template<bool DEC>
__global__ __launch_bounds__(1024, 4) void k_layer(
    float* __restrict__ h,
    const unsigned short* __restrict__ whi, const unsigned short* __restrict__ wlo,
    int lmat, const float* __restrict__ bc, const float* __restrict__ br,
    const int* __restrict__ poff_g, const int* __restrict__ prl_g,
    const float* __restrict__ pnorm_g, const float* __restrict__ psn_g,
    const int* __restrict__ ei, const float* __restrict__ ea,
    const float* __restrict__ We, const float* __restrict__ be,
    const float* __restrict__ Wd, const float* __restrict__ bd,
    float* __restrict__ out)
{
    __shared__ __align__(16) char sraw[DEC ? sizeof(SmemDec) : sizeof(SmemMid)];
    SmemMid& s = *reinterpret_cast<SmemMid*>(sraw);
    float* hf = DEC ? reinterpret_cast<SmemDec*>(sraw)->hf : nullptr;

    const int t = threadIdx.x;
    const int w = t >> 6, l = t & 63;
    const int cg = w & 7, rg = w >> 3;
    const int lr = l & 15, lq = l >> 4;
    const int col16 = 16 * cg + lr;

    if (t <= N_NODES) s.poff[t] = poff_g[t];
    if (t < N_EDGES) { s.prl[t] = prl_g[t]; s.pnorm[t] = pnorm_g[t]; }
    if (t < N_NODES) s.psn[t] = psn_g[t];

    // ---- W fragments (16 cols/wave): [mat][comp][ks] = 16 frags = 64 VGPR ----
    bf16x8 Wf[2][2][4];
#pragma unroll
    for (int mat = 0; mat < 2; ++mat) {
        const int mi = (mat == 0) ? lmat : 4;
#pragma unroll
        for (int ks = 0; ks < 4; ++ks) {
            const int off = mi * 16384 + col16 * HID + 32 * ks + 8 * lq;
            Wf[mat][0][ks] = *(const bf16x8*)(whi + off);
            Wf[mat][1][ks] = *(const bf16x8*)(wlo + off);
        }
    }
    const float bsum = bc[col16] + br[col16];
    __syncthreads();

    const long long blkrow0 = (long long)blockIdx.x * 32 * N_NODES;  // 32 graphs/block
    const int srow = t >> 5;            // stage row base (rows 0..31)
    const int sk = (t * 4) & 127;
    float4 pf[3];
    {
        const float4* hsrc = (const float4*)(h + blkrow0 * HID);
#pragma unroll
        for (int i = 0; i < 3; ++i) pf[i] = hsrc[t + 1024 * i];
    }

    for (int ci = 0; ci < 8; ++ci) {
        // ---- stage h -> bf16 hi/lo planes ----
#pragma unroll
        for (int i = 0; i < 3; ++i) {
            const int row = srow + 32 * i;
            float xs[4] = {pf[i].x, pf[i].y, pf[i].z, pf[i].w};
            unsigned short hs[4], ls[4];
#pragma unroll
            for (int j = 0; j < 4; ++j) {
                unsigned int u = __float_as_uint(xs[j]);
                hs[j] = (unsigned short)(u >> 16);
                float hfv = __uint_as_float(u & 0xFFFF0000u);
                ls[j] = (unsigned short)(__float_as_uint(xs[j] - hfv) >> 16);
            }
            *(ushort4*)&s.u.planes[0][row * ST + sk] = make_ushort4(hs[0], hs[1], hs[2], hs[3]);
            *(ushort4*)&s.u.planes[1][row * ST + sk] = make_ushort4(ls[0], ls[1], ls[2], ls[3]);
        }
        __syncthreads();

        // prefetch next chunk's h (hides HBM latency under MFMA)
        if (ci < 7) {
            const float4* nsrc = (const float4*)(h + (blkrow0 + (ci + 1) * 96) * HID);
#pragma unroll
            for (int i = 0; i < 3; ++i) pf[i] = nsrc[t + 1024 * i];
        }

        // ---- MFMA: accT = h@Wc, accR = h@Wr (3-pass split-bf16) ----
        f32x4 accT[3], accR[3];
#pragma unroll
        for (int mt = 0; mt < 3; ++mt) {
            accT[mt] = (f32x4){0.f, 0.f, 0.f, 0.f};
            accR[mt] = (f32x4){0.f, 0.f, 0.f, 0.f};
        }
#pragma unroll
        for (int ks = 0; ks < 4; ++ks) {
            const int ko = 32 * ks + 8 * lq;
#pragma unroll
            for (int mt = 0; mt < 3; ++mt) {
                const int row16 = 48 * rg + 16 * mt + lr;
                const bf16x8 ahi = *(const bf16x8*)&s.u.planes[0][row16 * ST + ko];
                const bf16x8 alo = *(const bf16x8*)&s.u.planes[1][row16 * ST + ko];
                accT[mt] = __builtin_amdgcn_mfma_f32_16x16x32_bf16(ahi, Wf[0][0][ks], accT[mt], 0, 0, 0);
                accT[mt] = __builtin_amdgcn_mfma_f32_16x16x32_bf16(alo, Wf[0][0][ks], accT[mt], 0, 0, 0);
                accT[mt] = __builtin_amdgcn_mfma_f32_16x16x32_bf16(ahi, Wf[0][1][ks], accT[mt], 0, 0, 0);
                accR[mt] = __builtin_amdgcn_mfma_f32_16x16x32_bf16(ahi, Wf[1][0][ks], accR[mt], 0, 0, 0);
                accR[mt] = __builtin_amdgcn_mfma_f32_16x16x32_bf16(alo, Wf[1][0][ks], accR[mt], 0, 0, 0);
                accR[mt] = __builtin_amdgcn_mfma_f32_16x16x32_bf16(ahi, Wf[1][1][ks], accR[mt], 0, 0, 0);
            }
        }
        __syncthreads();   // all h-plane reads done -> overlay tt

        // ---- write conv tile to LDS (C/D layout: col=lr, row=4*lq+j) ----
#pragma unroll
        for (int mt = 0; mt < 3; ++mt)
#pragma unroll
            for (int j = 0; j < 4; ++j)
                s.u.tt[(48 * rg + 16 * mt + 4 * lq + j) * TST + col16] = accT[mt][j];
        __syncthreads();

        // ---- aggregate + bias + residual + relu ----
        float* hdst = h + (blkrow0 + ci * 96) * HID;
#pragma unroll
        for (int mt = 0; mt < 3; ++mt)
#pragma unroll
            for (int j = 0; j < 4; ++j) {
                const int r48 = 16 * mt + 4 * lq + j;          // [0,48)
                const int gl2 = (r48 >= 24) ? 1 : 0;
                const int nn = r48 - 24 * gl2;
                const int gbase = (2 * rg + gl2) * 24;
                float v = bsum + accR[mt][j] + s.psn[nn] * accT[mt][j];
                const int pe = s.poff[nn + 1];
                for (int p = s.poff[nn]; p < pe; ++p)
                    v = fmaf(s.pnorm[p], s.u.tt[(gbase + s.prl[p]) * TST + col16], v);
                v = fmaxf(v, 0.f);
                if constexpr (DEC) hf[(gbase + nn) * HFST + col16] = v;
                else hdst[(gbase + nn) * HID + col16] = v;
            }

        if constexpr (DEC) {
            __syncthreads();   // hf complete
            // fused decoder: wave w handles edges 19*w..19*w+18 of this chunk's 304.
            // lane handles cols c0=l, c1=l+64; per-lane W_edge/W_dec/b_edge in regs.
            const int c0 = l, c1 = l + 64;
            float wef0[8], wef1[8];
#pragma unroll
            for (int f = 0; f < 8; ++f) {
                wef0[f] = We[f * HID + c0];
                wef1[f] = We[f * HID + c1];
            }
            const float wd00 = Wd[c0], wd01 = Wd[c1];
            const float wd10 = Wd[HID + c0], wd11 = Wd[HID + c1];
            const float wd20 = Wd[2 * HID + c0], wd21 = Wd[2 * HID + c1];
            const float be0 = be[c0], be1 = be[c1], bd0 = bd[0];
            for (int it = 0; it < 19; ++it) {
                const int e_loc = 19 * w + it;            // [0,304)
                const int gl = e_loc / 76, j = e_loc - gl * 76;
                const int g = blockIdx.x * 32 + ci * 4 + gl;
                const int e = g * N_EDGES + j;
                const int nrow = ei[e] - g * N_NODES;
                const int ncol = ei[TOT_E + e] - g * N_NODES;
                const float4 a0 = *(const float4*)(ea + (size_t)e * EDGE_F);
                const float4 a1 = *(const float4*)(ea + (size_t)e * EDGE_F + 4);
                float enc0 = be0 + We[(EDGE_F + j) * HID + c0];
                float enc1 = be1 + We[(EDGE_F + j) * HID + c1];
                enc0 = fmaf(a0.x, wef0[0], enc0); enc1 = fmaf(a0.x, wef1[0], enc1);
                enc0 = fmaf(a0.y, wef0[1], enc0); enc1 = fmaf(a0.y, wef1[1], enc1);
                enc0 = fmaf(a0.z, wef0[2], enc0); enc1 = fmaf(a0.z, wef1[2], enc1);
                enc0 = fmaf(a0.w, wef0[3], enc0); enc1 = fmaf(a0.w, wef1[3], enc1);
                enc0 = fmaf(a1.x, wef0[4], enc0); enc1 = fmaf(a1.x, wef1[4], enc1);
                enc0 = fmaf(a1.y, wef0[5], enc0); enc1 = fmaf(a1.y, wef1[5], enc1);
                enc0 = fmaf(a1.z, wef0[6], enc0); enc1 = fmaf(a1.z, wef1[6], enc1);
                enc0 = fmaf(a1.w, wef0[7], enc0); enc1 = fmaf(a1.w, wef1[7], enc1);
                enc0 = fmaxf(enc0, 0.f); enc1 = fmaxf(enc1, 0.f);
                float v = enc0 * wd20 + enc1 * wd21;
                v = fmaf(hf[(gl * 24 + nrow) * HFST + c0], wd00, v);
                v = fmaf(hf[(gl * 24 + nrow) * HFST + c1], wd01, v);
                v = fmaf(hf[(gl * 24 + ncol) * HFST + c0], wd10, v);
                v = fmaf(hf[(gl * 24 + ncol) * HFST + c1], wd11, v);
#pragma unroll
                for (int o = 32; o > 0; o >>= 1) v += __shfl_xor(v, o, 64);
                if (l == 0) out[e] = v + bd0;
            }
        }
        __syncthreads();   // tt (and hf) reads done before next chunk's writes
    }
}

extern "C" void kernel_launch(void* const* d_in, const int* in_sizes, int n_in,
                              void* d_out, int out_size, void* d_ws, size_t ws_size,
                              hipStream_t stream) {
    const float* x   = (const float*)d_in[0];
    const int*   ei  = (const int*)d_in[1];   // [2][TOT_E]
    const float* ea  = (const float*)d_in[2];
    /* d_in[3] = batch, unused */
    const float* Wn  = (const float*)d_in[4];
    const float* bn  = (const float*)d_in[5];
    const float* We  = (const float*)d_in[6];
    const float* be  = (const float*)d_in[7];
    const float* Wcv = (const float*)d_in[8];
    const float* bcv = (const float*)d_in[9];
    const float* Wr  = (const float*)d_in[10];
    const float* br  = (const float*)d_in[11];
    const float* Wd  = (const float*)d_in[12];
    const float* bd  = (const float*)d_in[13];
    float* out = (float*)d_out;

    char* ws = (char*)d_ws;
    float* h = (float*)ws;                                    // [TOT_N][128] fp32
    size_t hbytes = (size_t)TOT_N * HID * sizeof(float);      // ~100.7 MB
    unsigned short* whi = (unsigned short*)(ws + hbytes);     // 5*16384 bf16
    unsigned short* wlo = whi + 5 * 16384;
    int*   poff  = (int*)(wlo + 5 * 16384);
    int*   prl   = poff + 32;
    float* pnorm = (float*)(prl + 96);
    float* psn   = pnorm + 96;

    k_node_enc<<<TOT_N * HID / 256, 256, 0, stream>>>(x, Wn, bn, h);
    k_pattern<<<1, 128, 0, stream>>>(ei, poff, prl, pnorm, psn);
    k_wprep<<<5 * 16384 / 256, 256, 0, stream>>>(Wcv, Wr, whi, wlo);
    for (int l = 0; l < 3; ++l)
        k_layer<false><<<256, 1024, 0, stream>>>(h, whi, wlo, l, bcv + l * HID, br,
                                                 poff, prl, pnorm, psn,
                                                 ei, ea, We, be, Wd, bd, out);
    k_layer<true><<<256, 1024, 0, stream>>>(h, whi, wlo, 3, bcv + 3 * HID, br,
                                            poff, prl, pnorm, psn,
                                            ei, ea, We, be, Wd, bd, out);
}

// Round 5
// 502.396 us; speedup vs baseline: 5.0564x; 1.5119x over previous
//
#include <hip/hip_runtime.h>

typedef short bf16x8 __attribute__((ext_vector_type(8)));
typedef float f32x4  __attribute__((ext_vector_type(4)));

#define N_NODES 24
#define N_EDGES 76
#define N_GRAPHS 8192
#define HID 128
#define NODE_F 16
#define EDGE_F 8
#define TOT_N (N_NODES * N_GRAPHS)   /* 196608 */
#define TOT_E (N_EDGES * N_GRAPHS)   /* 622592 */
#define ST 136        /* bf16 h-plane stride (ushorts): 272B rows, <=2-way on b128 */
#define TST 130       /* fp32 t-tile stride: lq-groups offset 8 banks, <=2-way */
#define GPB 2         /* graphs per block */
#define M 48          /* rows per block = GPB*24 */

// ------- topology pattern (identical across graphs): CSR + norms from graph 0 -------
__global__ void k_pattern(const int* __restrict__ ei, int* __restrict__ poff,
                          int* __restrict__ prl, float* __restrict__ pnorm,
                          float* __restrict__ psn)
{
    __shared__ int cnt[N_NODES], off[N_NODES + 1], loc[N_NODES];
    __shared__ float dinv[N_NODES];
    int t = threadIdx.x;
    if (t < N_NODES) cnt[t] = 0;
    __syncthreads();
    if (t < N_EDGES) atomicAdd(&cnt[ei[TOT_E + t]], 1);   // in-degree by col
    __syncthreads();
    if (t == 0) {
        int s = 0;
        for (int n = 0; n < N_NODES; ++n) { off[n] = s; s += cnt[n]; }
        off[N_NODES] = s;
    }
    __syncthreads();
    if (t < N_NODES) {
        loc[t] = off[t];
        float deg = (float)(cnt[t] + 1);   // +1 self loop
        dinv[t] = rsqrtf(deg);
        psn[t]  = 1.f / deg;               // self-loop norm = dinv^2
    }
    __syncthreads();
    if (t < N_EDGES) {
        int r = ei[t], cc = ei[TOT_E + t];
        int p = atomicAdd(&loc[cc], 1);
        prl[p]   = r;
        pnorm[p] = dinv[r] * dinv[cc];
    }
    if (t <= N_NODES) poff[t] = off[t];
}

// ------- W prep: transpose to [c][k] and split fp32 -> bf16 hi/lo planes -------
__global__ __launch_bounds__(256) void k_wprep(
    const float* __restrict__ Wcv, const float* __restrict__ Wr,
    unsigned short* __restrict__ whi, unsigned short* __restrict__ wlo)
{
    int idx = blockIdx.x * 256 + threadIdx.x;    // [0, 5*16384)
    int m = idx >> 14, rem = idx & 16383;
    int k = rem >> 7, c = rem & 127;
    const float* src = (m < 4) ? (Wcv + m * 16384) : Wr;
    float x = src[k * HID + c];
    unsigned int u = __float_as_uint(x);
    unsigned short hi = (unsigned short)(u >> 16);
    float hf = __uint_as_float(u & 0xFFFF0000u);
    unsigned short lo = (unsigned short)(__float_as_uint(x - hf) >> 16);
    whi[m * 16384 + c * HID + k] = hi;
    wlo[m * 16384 + c * HID + k] = lo;
}

__device__ __forceinline__ void split2(float xv, unsigned short& hs, unsigned short& ls)
{
    unsigned int u = __float_as_uint(xv);
    hs = (unsigned short)(u >> 16);
    float hf = __uint_as_float(u & 0xFFFF0000u);
    ls = (unsigned short)(__float_as_uint(xv - hf) >> 16);
}

// ---------------- fully fused GNN: enc + 4 layers + decoder, h resident in LDS ----------------
// 512 thr = 8 waves; wave w owns 16 cols (col16 = 16w+lr), all 48 rows (3 mt tiles).
// LDS ~51.9 KB -> 2 blocks/CU (16 waves/CU). Inter-layer h never touches global.
struct Smem {
    unsigned short planes[2][M * ST];   // h as bf16 hi/lo (26112 B); x-tile staged in tt
    float tt[M * TST];                  // conv result tile (24960 B); also x [48][16] at start
    int poff[N_NODES + 1];
    int prl[N_EDGES];
    float pnorm[N_EDGES];
    float psn[N_NODES];
};

__global__ __launch_bounds__(512, 4) void k_fused(
    const float* __restrict__ x, const float* __restrict__ Wn,
    const float* __restrict__ bn,
    const unsigned short* __restrict__ whi, const unsigned short* __restrict__ wlo,
    const float* __restrict__ bcv, const float* __restrict__ br,
    const int* __restrict__ poff_g, const int* __restrict__ prl_g,
    const float* __restrict__ pnorm_g, const float* __restrict__ psn_g,
    const int* __restrict__ ei, const float* __restrict__ ea,
    const float* __restrict__ We, const float* __restrict__ be,
    const float* __restrict__ Wd, const float* __restrict__ bd,
    float* __restrict__ out)
{
    __shared__ Smem s;
    const int t = threadIdx.x;
    const int w = t >> 6, l = t & 63;
    const int lr = l & 15, lq = l >> 4;
    const int col16 = 16 * w + lr;

    if (t <= N_NODES) s.poff[t] = poff_g[t];
    if (t < N_EDGES) { s.prl[t] = prl_g[t]; s.pnorm[t] = pnorm_g[t]; }
    if (t < N_NODES) s.psn[t] = psn_g[t];

    // W_res fragments: persist across all layers (32 VGPR)
    bf16x8 Wr_[2][4];
#pragma unroll
    for (int ks = 0; ks < 4; ++ks) {
        const int off = 4 * 16384 + col16 * HID + 32 * ks + 8 * lq;
        Wr_[0][ks] = *(const bf16x8*)(whi + off);
        Wr_[1][ks] = *(const bf16x8*)(wlo + off);
    }
    const float brc = br[col16];

    // ---- stage x tile (48x16 fp32 = 192 float4) into tt region ----
    const long long n0 = (long long)blockIdx.x * M;
    if (t < 192) ((float4*)s.tt)[t] = ((const float4*)(x + n0 * NODE_F))[t];
    __syncthreads();

    // ---- node encoder: h0 = relu(x @ Wn + bn) -> planes ----
    {
        const int c = t & 127, tq = t >> 7;       // tq wave-uniform
        float wn[NODE_F];
#pragma unroll
        for (int k = 0; k < NODE_F; ++k) wn[k] = Wn[k * HID + c];
        const float bnc = bn[c];
        const float* xt = s.tt;                    // [48][16]
#pragma unroll
        for (int jj = 0; jj < 12; ++jj) {
            const int n = tq * 12 + jj;
            float acc = bnc;
#pragma unroll
            for (int k = 0; k < NODE_F; ++k) acc = fmaf(xt[n * NODE_F + k], wn[k], acc);
            acc = fmaxf(acc, 0.f);
            unsigned short hs, ls;
            split2(acc, hs, ls);
            s.planes[0][n * ST + c] = hs;
            s.planes[1][n * ST + c] = ls;
        }
    }
    __syncthreads();

    // ---- 4 GCN layers, h resident in LDS ----
    for (int lyr = 0; lyr < 4; ++lyr) {
        // conv-W fragments for this layer (32 VGPR, L2-hot reload)
        bf16x8 Wc_[2][4];
#pragma unroll
        for (int ks = 0; ks < 4; ++ks) {
            const int off = lyr * 16384 + col16 * HID + 32 * ks + 8 * lq;
            Wc_[0][ks] = *(const bf16x8*)(whi + off);
            Wc_[1][ks] = *(const bf16x8*)(wlo + off);
        }
        const float bsum = bcv[lyr * HID + col16] + brc;

        // MFMA: accT = h@Wc, accR = h@Wr (3-pass split-bf16)
        f32x4 accT[3], accR[3];
#pragma unroll
        for (int mt = 0; mt < 3; ++mt) {
            accT[mt] = (f32x4){0.f, 0.f, 0.f, 0.f};
            accR[mt] = (f32x4){0.f, 0.f, 0.f, 0.f};
        }
#pragma unroll
        for (int ks = 0; ks < 4; ++ks) {
            const int ko = 32 * ks + 8 * lq;
#pragma unroll
            for (int mt = 0; mt < 3; ++mt) {
                const int row16 = 16 * mt + lr;
                const bf16x8 ahi = *(const bf16x8*)&s.planes[0][row16 * ST + ko];
                const bf16x8 alo = *(const bf16x8*)&s.planes[1][row16 * ST + ko];
                accT[mt] = __builtin_amdgcn_mfma_f32_16x16x32_bf16(ahi, Wc_[0][ks], accT[mt], 0, 0, 0);
                accT[mt] = __builtin_amdgcn_mfma_f32_16x16x32_bf16(alo, Wc_[0][ks], accT[mt], 0, 0, 0);
                accT[mt] = __builtin_amdgcn_mfma_f32_16x16x32_bf16(ahi, Wc_[1][ks], accT[mt], 0, 0, 0);
                accR[mt] = __builtin_amdgcn_mfma_f32_16x16x32_bf16(ahi, Wr_[0][ks], accR[mt], 0, 0, 0);
                accR[mt] = __builtin_amdgcn_mfma_f32_16x16x32_bf16(alo, Wr_[0][ks], accR[mt], 0, 0, 0);
                accR[mt] = __builtin_amdgcn_mfma_f32_16x16x32_bf16(ahi, Wr_[1][ks], accR[mt], 0, 0, 0);
            }
        }
        // write conv tile to LDS (C/D layout: col=lr, row=4*lq+j); tt free since barrier
#pragma unroll
        for (int mt = 0; mt < 3; ++mt)
#pragma unroll
            for (int j = 0; j < 4; ++j)
                s.tt[(16 * mt + 4 * lq + j) * TST + col16] = accT[mt][j];
        __syncthreads();

        // aggregate + bias + residual + relu -> new h planes (h^l dead after MFMA)
#pragma unroll
        for (int mt = 0; mt < 3; ++mt)
#pragma unroll
            for (int j = 0; j < 4; ++j) {
                const int r48 = 16 * mt + 4 * lq + j;          // [0,48)
                const int gl2 = (r48 >= 24) ? 1 : 0;
                const int nn = r48 - 24 * gl2;
                const int gbase = 24 * gl2;
                float v = bsum + accR[mt][j] + s.psn[nn] * accT[mt][j];
                const int pe = s.poff[nn + 1];
                for (int p = s.poff[nn]; p < pe; ++p)
                    v = fmaf(s.pnorm[p], s.tt[(gbase + s.prl[p]) * TST + col16], v);
                v = fmaxf(v, 0.f);
                unsigned short hs, ls;
                split2(v, hs, ls);
                s.planes[0][r48 * ST + col16] = hs;
                s.planes[1][r48 * ST + col16] = ls;
            }
        __syncthreads();
    }

    // ---- fused decoder: 152 edges, 19 per wave; h read from planes ----
    {
        const int c0 = l, c1 = l + 64;
        float wef0[8], wef1[8];
#pragma unroll
        for (int f = 0; f < 8; ++f) {
            wef0[f] = We[f * HID + c0];
            wef1[f] = We[f * HID + c1];
        }
        const float wd00 = Wd[c0], wd01 = Wd[c1];
        const float wd10 = Wd[HID + c0], wd11 = Wd[HID + c1];
        const float wd20 = Wd[2 * HID + c0], wd21 = Wd[2 * HID + c1];
        const float be0 = be[c0], be1 = be[c1], bd0 = bd[0];
        for (int it = 0; it < 19; ++it) {
            const int e_loc = 19 * w + it;            // [0,152)
            const int gl = (e_loc >= 76) ? 1 : 0;
            const int j = e_loc - 76 * gl;
            const int g = blockIdx.x * GPB + gl;
            const int e = g * N_EDGES + j;
            const int nrow = ei[e] - g * N_NODES;
            const int ncol = ei[TOT_E + e] - g * N_NODES;
            const float4 a0 = *(const float4*)(ea + (size_t)e * EDGE_F);
            const float4 a1 = *(const float4*)(ea + (size_t)e * EDGE_F + 4);
            float enc0 = be0 + We[(EDGE_F + j) * HID + c0];
            float enc1 = be1 + We[(EDGE_F + j) * HID + c1];
            enc0 = fmaf(a0.x, wef0[0], enc0); enc1 = fmaf(a0.x, wef1[0], enc1);
            enc0 = fmaf(a0.y, wef0[1], enc0); enc1 = fmaf(a0.y, wef1[1], enc1);
            enc0 = fmaf(a0.z, wef0[2], enc0); enc1 = fmaf(a0.z, wef1[2], enc1);
            enc0 = fmaf(a0.w, wef0[3], enc0); enc1 = fmaf(a0.w, wef1[3], enc1);
            enc0 = fmaf(a1.x, wef0[4], enc0); enc1 = fmaf(a1.x, wef1[4], enc1);
            enc0 = fmaf(a1.y, wef0[5], enc0); enc1 = fmaf(a1.y, wef1[5], enc1);
            enc0 = fmaf(a1.z, wef0[6], enc0); enc1 = fmaf(a1.z, wef1[6], enc1);
            enc0 = fmaf(a1.w, wef0[7], enc0); enc1 = fmaf(a1.w, wef1[7], enc1);
            enc0 = fmaxf(enc0, 0.f); enc1 = fmaxf(enc1, 0.f);
            float v = enc0 * wd20 + enc1 * wd21;
            const int rr = gl * N_NODES + nrow, rc = gl * N_NODES + ncol;
            // reconstruct fp32 h from hi/lo planes
            float hr0 = __uint_as_float((unsigned int)s.planes[0][rr * ST + c0] << 16)
                      + __uint_as_float((unsigned int)s.planes[1][rr * ST + c0] << 16);
            float hr1 = __uint_as_float((unsigned int)s.planes[0][rr * ST + c1] << 16)
                      + __uint_as_float((unsigned int)s.planes[1][rr * ST + c1] << 16);
            float hc0 = __uint_as_float((unsigned int)s.planes[0][rc * ST + c0] << 16)
                      + __uint_as_float((unsigned int)s.planes[1][rc * ST + c0] << 16);
            float hc1 = __uint_as_float((unsigned int)s.planes[0][rc * ST + c1] << 16)
                      + __uint_as_float((unsigned int)s.planes[1][rc * ST + c1] << 16);
            v = fmaf(hr0, wd00, v);
            v = fmaf(hr1, wd01, v);
            v = fmaf(hc0, wd10, v);
            v = fmaf(hc1, wd11, v);
#pragma unroll
            for (int o = 32; o > 0; o >>= 1) v += __shfl_xor(v, o, 64);
            if (l == 0) out[e] = v + bd0;
        }
    }
}

extern "C" void kernel_launch(void* const* d_in, const int* in_sizes, int n_in,
                              void* d_out, int out_size, void* d_ws, size_t ws_size,
                              hipStream_t stream) {
    const float* x   = (const float*)d_in[0];
    const int*   ei  = (const int*)d_in[1];   // [2][TOT_E]
    const float* ea  = (const float*)d_in[2];
    /* d_in[3] = batch, unused */
    const float* Wn  = (const float*)d_in[4];
    const float* bn  = (const float*)d_in[5];
    const float* We  = (const float*)d_in[6];
    const float* be  = (const float*)d_in[7];
    const float* Wcv = (const float*)d_in[8];
    const float* bcv = (const float*)d_in[9];
    const float* Wr  = (const float*)d_in[10];
    const float* br  = (const float*)d_in[11];
    const float* Wd  = (const float*)d_in[12];
    const float* bd  = (const float*)d_in[13];
    float* out = (float*)d_out;

    char* ws = (char*)d_ws;
    unsigned short* whi = (unsigned short*)ws;                // 5*16384 bf16
    unsigned short* wlo = whi + 5 * 16384;
    int*   poff  = (int*)(wlo + 5 * 16384);
    int*   prl   = poff + 32;
    float* pnorm = (float*)(prl + 96);
    float* psn   = pnorm + 96;

    k_pattern<<<1, 128, 0, stream>>>(ei, poff, prl, pnorm, psn);
    k_wprep<<<5 * 16384 / 256, 256, 0, stream>>>(Wcv, Wr, whi, wlo);
    k_fused<<<N_GRAPHS / GPB, 512, 0, stream>>>(x, Wn, bn, whi, wlo, bcv, br,
                                                poff, prl, pnorm, psn,
                                                ei, ea, We, be, Wd, bd, out);
}

// Round 6
// 328.836 us; speedup vs baseline: 7.7252x; 1.5278x over previous
//
#include <hip/hip_runtime.h>

typedef short bf16x8 __attribute__((ext_vector_type(8)));
typedef float f32x4  __attribute__((ext_vector_type(4)));

#define N_NODES 24
#define N_EDGES 76
#define N_GRAPHS 8192
#define HID 128
#define NODE_F 16
#define EDGE_F 8
#define TOT_E (N_EDGES * N_GRAPHS)   /* 622592 */
#define ST 136     /* bf16 h-plane stride (ushorts) */
#define TT 56      /* ttT (t transposed) stride in ushorts: bank-free b64 writes / b128 reads */
#define AST 72     /* Ap (block-diag adjacency) stride in ushorts: (lr+lq)%8 uniform on b128 */
#define GPB 2      /* graphs per block */
#define M 48       /* rows per block = GPB*24 */

// ------- static normalized adjacency (identical topology across graphs) -------
// Builds zero-padded block-diag 48x72 hi/lo split-bf16 A with self-loop diagonal:
// agg(t)[n] = sum_m A[n][m] * t[m]  ==  GCN symmetric-normalized segment_sum.
__global__ void k_pattern(const int* __restrict__ ei, unsigned short* __restrict__ Ag)
{
    __shared__ float A[N_NODES][N_NODES];
    __shared__ int cnt[N_NODES];
    __shared__ float dinv[N_NODES];
    const int t = threadIdx.x;   // 128 threads
    for (int i = t; i < N_NODES * N_NODES; i += 128) ((float*)A)[i] = 0.f;
    if (t < N_NODES) cnt[t] = 0;
    __syncthreads();
    if (t < N_EDGES) atomicAdd(&cnt[ei[TOT_E + t]], 1);   // in-degree by col
    __syncthreads();
    if (t < N_NODES) dinv[t] = rsqrtf((float)(cnt[t] + 1));  // +1 self loop
    __syncthreads();
    if (t < N_EDGES) {
        const int r = ei[t], c = ei[TOT_E + t];              // graph-0 ids are local
        atomicAdd(&A[c][r], dinv[r] * dinv[c]);              // duplicates accumulate
    }
    __syncthreads();
    if (t < N_NODES) A[t][t] += dinv[t] * dinv[t];           // self-loop term
    __syncthreads();
    for (int i = t; i < M * AST; i += 128) {
        const int row = i / AST, k = i - row * AST;
        float v = 0.f;
        if (row < N_NODES) { if (k < N_NODES) v = A[row][k]; }
        else if (k >= N_NODES && k < 2 * N_NODES) v = A[row - N_NODES][k - N_NODES];
        const unsigned int u = __float_as_uint(v);
        const unsigned short hi = (unsigned short)(u >> 16);
        const float hf = __uint_as_float(u & 0xFFFF0000u);
        const unsigned short lo = (unsigned short)(__float_as_uint(v - hf) >> 16);
        Ag[i] = hi;
        Ag[M * AST + i] = lo;
    }
}

// ------- W prep: transpose to [c][k] and split fp32 -> bf16 hi/lo planes -------
__global__ __launch_bounds__(256) void k_wprep(
    const float* __restrict__ Wcv, const float* __restrict__ Wr,
    unsigned short* __restrict__ whi, unsigned short* __restrict__ wlo)
{
    int idx = blockIdx.x * 256 + threadIdx.x;    // [0, 5*16384)
    int m = idx >> 14, rem = idx & 16383;
    int k = rem >> 7, c = rem & 127;
    const float* src = (m < 4) ? (Wcv + m * 16384) : Wr;
    float x = src[k * HID + c];
    unsigned int u = __float_as_uint(x);
    unsigned short hi = (unsigned short)(u >> 16);
    float hf = __uint_as_float(u & 0xFFFF0000u);
    unsigned short lo = (unsigned short)(__float_as_uint(x - hf) >> 16);
    whi[m * 16384 + c * HID + k] = hi;
    wlo[m * 16384 + c * HID + k] = lo;
}

__device__ __forceinline__ void split2(float xv, unsigned short& hs, unsigned short& ls)
{
    unsigned int u = __float_as_uint(xv);
    hs = (unsigned short)(u >> 16);
    float hf = __uint_as_float(u & 0xFFFF0000u);
    ls = (unsigned short)(__float_as_uint(xv - hf) >> 16);
}

// ---------------- fully fused GNN: enc + 4x(MFMA conv + MFMA agg) + decoder ----------------
// 512 thr = 8 waves; wave w owns 16 cols (col16=16w+lr), all 48 rows (3 mt tiles).
// Aggregation done by MFMA against the static block-diag adjacency (no CSR, no divergence).
struct Smem {
    unsigned short planes[2][M * ST];       // h as bf16 hi/lo        (26112 B)
    unsigned short ttT[2][128 * TT + 8];    // t transposed hi/lo     (28704 B); x staged here first
    unsigned short Ap[2][M * AST];          // block-diag A hi/lo     (13824 B)
};                                          // total 68640 B -> 2 blocks/CU

__global__ __launch_bounds__(512, 4) void k_fused(
    const float* __restrict__ x, const float* __restrict__ Wn,
    const float* __restrict__ bn,
    const unsigned short* __restrict__ whi, const unsigned short* __restrict__ wlo,
    const unsigned short* __restrict__ Ag,
    const float* __restrict__ bcv, const float* __restrict__ br,
    const int* __restrict__ ei, const float* __restrict__ ea,
    const float* __restrict__ We, const float* __restrict__ be,
    const float* __restrict__ Wd, const float* __restrict__ bd,
    float* __restrict__ out)
{
    __shared__ Smem s;
    const int t = threadIdx.x;
    const int w = t >> 6, l = t & 63;
    const int lr = l & 15, lq = l >> 4;
    const int col16 = 16 * w + lr;

    // persistent W_res fragments (32 VGPR)
    bf16x8 Wr_[2][4];
#pragma unroll
    for (int ks = 0; ks < 4; ++ks) {
        const int off = 4 * 16384 + col16 * HID + 32 * ks + 8 * lq;
        Wr_[0][ks] = *(const bf16x8*)(whi + off);
        Wr_[1][ks] = *(const bf16x8*)(wlo + off);
    }
    const float brc = br[col16];

    // stage x tile (48x16 fp32 = 192 float4) into ttT region + stage Ap
    const long long n0 = (long long)blockIdx.x * M;
    if (t < 192) ((float4*)s.ttT)[t] = ((const float4*)(x + n0 * NODE_F))[t];
    {
        const uint4* src = (const uint4*)Ag;
        uint4* dst = (uint4*)s.Ap;
#pragma unroll 2
        for (int i = t; i < 2 * M * AST / 8; i += 512) dst[i] = src[i];
    }
    __syncthreads();

    // ---- node encoder: h0 = relu(x @ Wn + bn) -> planes ----
    {
        const int c = t & 127, tq = t >> 7;       // tq wave-uniform
        float wn[NODE_F];
#pragma unroll
        for (int k = 0; k < NODE_F; ++k) wn[k] = Wn[k * HID + c];
        const float bnc = bn[c];
        const float* xt = (const float*)s.ttT;     // [48][16]
#pragma unroll
        for (int jj = 0; jj < 12; ++jj) {
            const int n = tq * 12 + jj;
            float acc = bnc;
#pragma unroll
            for (int k = 0; k < NODE_F; ++k) acc = fmaf(xt[n * NODE_F + k], wn[k], acc);
            acc = fmaxf(acc, 0.f);
            unsigned short hs, ls;
            split2(acc, hs, ls);
            s.planes[0][n * ST + c] = hs;
            s.planes[1][n * ST + c] = ls;
        }
    }
    __syncthreads();

    // zero ttT pad regions (k=48..55 per col + tails) so MFMA K-overrun reads are finite.
    // t-value region (k<48) is written every layer; pads never collide with t writes.
    if (t < 256) {
        *(uint4*)&s.ttT[t >> 7][(t & 127) * TT + 48] = make_uint4(0u, 0u, 0u, 0u);
    } else if (t < 258) {
        *(uint4*)&s.ttT[t - 256][128 * TT] = make_uint4(0u, 0u, 0u, 0u);
    }

    // ---- 4 GCN layers, h resident in LDS; agg via MFMA with block-diag A ----
    for (int lyr = 0; lyr < 4; ++lyr) {
        bf16x8 Wc_[2][4];
#pragma unroll
        for (int ks = 0; ks < 4; ++ks) {
            const int off = lyr * 16384 + col16 * HID + 32 * ks + 8 * lq;
            Wc_[0][ks] = *(const bf16x8*)(whi + off);
            Wc_[1][ks] = *(const bf16x8*)(wlo + off);
        }
        const float bsum = bcv[lyr * HID + col16] + brc;

        // conv + residual matmuls: accT = h@Wc, accR = h@Wr (3-pass split-bf16)
        f32x4 accT[3], accR[3];
#pragma unroll
        for (int mt = 0; mt < 3; ++mt) {
            accT[mt] = (f32x4){0.f, 0.f, 0.f, 0.f};
            accR[mt] = (f32x4){0.f, 0.f, 0.f, 0.f};
        }
#pragma unroll
        for (int ks = 0; ks < 4; ++ks) {
            const int ko = 32 * ks + 8 * lq;
#pragma unroll
            for (int mt = 0; mt < 3; ++mt) {
                const int row16 = 16 * mt + lr;
                const bf16x8 ahi = *(const bf16x8*)&s.planes[0][row16 * ST + ko];
                const bf16x8 alo = *(const bf16x8*)&s.planes[1][row16 * ST + ko];
                accT[mt] = __builtin_amdgcn_mfma_f32_16x16x32_bf16(ahi, Wc_[0][ks], accT[mt], 0, 0, 0);
                accT[mt] = __builtin_amdgcn_mfma_f32_16x16x32_bf16(alo, Wc_[0][ks], accT[mt], 0, 0, 0);
                accT[mt] = __builtin_amdgcn_mfma_f32_16x16x32_bf16(ahi, Wc_[1][ks], accT[mt], 0, 0, 0);
                accR[mt] = __builtin_amdgcn_mfma_f32_16x16x32_bf16(ahi, Wr_[0][ks], accR[mt], 0, 0, 0);
                accR[mt] = __builtin_amdgcn_mfma_f32_16x16x32_bf16(alo, Wr_[0][ks], accR[mt], 0, 0, 0);
                accR[mt] = __builtin_amdgcn_mfma_f32_16x16x32_bf16(ahi, Wr_[1][ks], accR[mt], 0, 0, 0);
            }
        }

        // write t TRANSPOSED as bf16 hi/lo: ttT[col][k], k = C/D row = 16mt+4lq+j
#pragma unroll
        for (int mt = 0; mt < 3; ++mt) {
            unsigned short hs[4], ls[4];
#pragma unroll
            for (int j = 0; j < 4; ++j) split2(accT[mt][j], hs[j], ls[j]);
            *(ushort4*)&s.ttT[0][col16 * TT + 16 * mt + 4 * lq] = make_ushort4(hs[0], hs[1], hs[2], hs[3]);
            *(ushort4*)&s.ttT[1][col16 * TT + 16 * mt + 4 * lq] = make_ushort4(ls[0], ls[1], ls[2], ls[3]);
        }
        __syncthreads();

        // aggregation matmul: accF = Ahi@thi + Alo@thi + Ahi@tlo + accR (C-chained)
        bf16x8 Th[2], Tl[2];
#pragma unroll
        for (int ks = 0; ks < 2; ++ks) {
            Th[ks] = *(const bf16x8*)&s.ttT[0][col16 * TT + 32 * ks + 8 * lq];
            Tl[ks] = *(const bf16x8*)&s.ttT[1][col16 * TT + 32 * ks + 8 * lq];
        }
        f32x4 accF[3];
#pragma unroll
        for (int mt = 0; mt < 3; ++mt) {
            const int arow = (16 * mt + lr) * AST + 8 * lq;
            accF[mt] = accR[mt];
#pragma unroll
            for (int ks = 0; ks < 2; ++ks) {
                const bf16x8 Ah = *(const bf16x8*)&s.Ap[0][arow + 32 * ks];
                const bf16x8 Al = *(const bf16x8*)&s.Ap[1][arow + 32 * ks];
                accF[mt] = __builtin_amdgcn_mfma_f32_16x16x32_bf16(Ah, Th[ks], accF[mt], 0, 0, 0);
                accF[mt] = __builtin_amdgcn_mfma_f32_16x16x32_bf16(Al, Th[ks], accF[mt], 0, 0, 0);
                accF[mt] = __builtin_amdgcn_mfma_f32_16x16x32_bf16(Ah, Tl[ks], accF[mt], 0, 0, 0);
            }
        }

        // bias + relu -> new h planes
#pragma unroll
        for (int mt = 0; mt < 3; ++mt)
#pragma unroll
            for (int j = 0; j < 4; ++j) {
                const int r48 = 16 * mt + 4 * lq + j;
                float v = fmaxf(bsum + accF[mt][j], 0.f);
                unsigned short hs, ls;
                split2(v, hs, ls);
                s.planes[0][r48 * ST + col16] = hs;
                s.planes[1][r48 * ST + col16] = ls;
            }
        __syncthreads();
    }

    // ---- fused decoder: 152 edges, 19 per wave; h read from planes ----
    {
        const int c0 = l, c1 = l + 64;
        float wef0[8], wef1[8];
#pragma unroll
        for (int f = 0; f < 8; ++f) {
            wef0[f] = We[f * HID + c0];
            wef1[f] = We[f * HID + c1];
        }
        const float wd00 = Wd[c0], wd01 = Wd[c1];
        const float wd10 = Wd[HID + c0], wd11 = Wd[HID + c1];
        const float wd20 = Wd[2 * HID + c0], wd21 = Wd[2 * HID + c1];
        const float be0 = be[c0], be1 = be[c1], bd0 = bd[0];
        for (int it = 0; it < 19; ++it) {
            const int e_loc = 19 * w + it;            // [0,152)
            const int gl = (e_loc >= 76) ? 1 : 0;
            const int j = e_loc - 76 * gl;
            const int g = blockIdx.x * GPB + gl;
            const int e = g * N_EDGES + j;
            const int nrow = ei[e] - g * N_NODES;
            const int ncol = ei[TOT_E + e] - g * N_NODES;
            const float4 a0 = *(const float4*)(ea + (size_t)e * EDGE_F);
            const float4 a1 = *(const float4*)(ea + (size_t)e * EDGE_F + 4);
            float enc0 = be0 + We[(EDGE_F + j) * HID + c0];
            float enc1 = be1 + We[(EDGE_F + j) * HID + c1];
            enc0 = fmaf(a0.x, wef0[0], enc0); enc1 = fmaf(a0.x, wef1[0], enc1);
            enc0 = fmaf(a0.y, wef0[1], enc0); enc1 = fmaf(a0.y, wef1[1], enc1);
            enc0 = fmaf(a0.z, wef0[2], enc0); enc1 = fmaf(a0.z, wef1[2], enc1);
            enc0 = fmaf(a0.w, wef0[3], enc0); enc1 = fmaf(a0.w, wef1[3], enc1);
            enc0 = fmaf(a1.x, wef0[4], enc0); enc1 = fmaf(a1.x, wef1[4], enc1);
            enc0 = fmaf(a1.y, wef0[5], enc0); enc1 = fmaf(a1.y, wef1[5], enc1);
            enc0 = fmaf(a1.z, wef0[6], enc0); enc1 = fmaf(a1.z, wef1[6], enc1);
            enc0 = fmaf(a1.w, wef0[7], enc0); enc1 = fmaf(a1.w, wef1[7], enc1);
            enc0 = fmaxf(enc0, 0.f); enc1 = fmaxf(enc1, 0.f);
            float v = enc0 * wd20 + enc1 * wd21;
            const int rr = gl * N_NODES + nrow, rc = gl * N_NODES + ncol;
            float hr0 = __uint_as_float((unsigned int)s.planes[0][rr * ST + c0] << 16)
                      + __uint_as_float((unsigned int)s.planes[1][rr * ST + c0] << 16);
            float hr1 = __uint_as_float((unsigned int)s.planes[0][rr * ST + c1] << 16)
                      + __uint_as_float((unsigned int)s.planes[1][rr * ST + c1] << 16);
            float hc0 = __uint_as_float((unsigned int)s.planes[0][rc * ST + c0] << 16)
                      + __uint_as_float((unsigned int)s.planes[1][rc * ST + c0] << 16);
            float hc1 = __uint_as_float((unsigned int)s.planes[0][rc * ST + c1] << 16)
                      + __uint_as_float((unsigned int)s.planes[1][rc * ST + c1] << 16);
            v = fmaf(hr0, wd00, v);
            v = fmaf(hr1, wd01, v);
            v = fmaf(hc0, wd10, v);
            v = fmaf(hc1, wd11, v);
#pragma unroll
            for (int o = 32; o > 0; o >>= 1) v += __shfl_xor(v, o, 64);
            if (l == 0) out[e] = v + bd0;
        }
    }
}

extern "C" void kernel_launch(void* const* d_in, const int* in_sizes, int n_in,
                              void* d_out, int out_size, void* d_ws, size_t ws_size,
                              hipStream_t stream) {
    const float* x   = (const float*)d_in[0];
    const int*   ei  = (const int*)d_in[1];   // [2][TOT_E]
    const float* ea  = (const float*)d_in[2];
    /* d_in[3] = batch, unused */
    const float* Wn  = (const float*)d_in[4];
    const float* bn  = (const float*)d_in[5];
    const float* We  = (const float*)d_in[6];
    const float* be  = (const float*)d_in[7];
    const float* Wcv = (const float*)d_in[8];
    const float* bcv = (const float*)d_in[9];
    const float* Wr  = (const float*)d_in[10];
    const float* br  = (const float*)d_in[11];
    const float* Wd  = (const float*)d_in[12];
    const float* bd  = (const float*)d_in[13];
    float* out = (float*)d_out;

    char* ws = (char*)d_ws;
    unsigned short* whi = (unsigned short*)ws;                // 5*16384 bf16
    unsigned short* wlo = whi + 5 * 16384;
    unsigned short* Ag  = wlo + 5 * 16384;                    // 2*48*72 bf16

    k_pattern<<<1, 128, 0, stream>>>(ei, Ag);
    k_wprep<<<5 * 16384 / 256, 256, 0, stream>>>(Wcv, Wr, whi, wlo);
    k_fused<<<N_GRAPHS / GPB, 512, 0, stream>>>(x, Wn, bn, whi, wlo, Ag, bcv, br,
                                                ei, ea, We, be, Wd, bd, out);
}

// Round 7
// 325.105 us; speedup vs baseline: 7.8139x; 1.0115x over previous
//
#include <hip/hip_runtime.h>

typedef short bf16x8 __attribute__((ext_vector_type(8)));
typedef float f32x4  __attribute__((ext_vector_type(4)));

#define N_NODES 24
#define N_EDGES 76
#define N_GRAPHS 8192
#define HID 128
#define NODE_F 16
#define EDGE_F 8
#define TOT_E (N_EDGES * N_GRAPHS)   /* 622592 */
#define ST 136     /* bf16 h-plane stride (ushorts) */
#define TT 56      /* ttT (t transposed) stride in ushorts: bank-free b64 writes / b128 reads */
#define AST 72     /* Ap (block-diag adjacency) stride in ushorts */
#define GPB 2      /* graphs per block */
#define M 48       /* rows per block = GPB*24 */

// ------- static normalized adjacency (identical topology across graphs) -------
__global__ void k_pattern(const int* __restrict__ ei, unsigned short* __restrict__ Ag)
{
    __shared__ float A[N_NODES][N_NODES];
    __shared__ int cnt[N_NODES];
    __shared__ float dinv[N_NODES];
    const int t = threadIdx.x;   // 128 threads
    for (int i = t; i < N_NODES * N_NODES; i += 128) ((float*)A)[i] = 0.f;
    if (t < N_NODES) cnt[t] = 0;
    __syncthreads();
    if (t < N_EDGES) atomicAdd(&cnt[ei[TOT_E + t]], 1);   // in-degree by col
    __syncthreads();
    if (t < N_NODES) dinv[t] = rsqrtf((float)(cnt[t] + 1));  // +1 self loop
    __syncthreads();
    if (t < N_EDGES) {
        const int r = ei[t], c = ei[TOT_E + t];              // graph-0 ids are local
        atomicAdd(&A[c][r], dinv[r] * dinv[c]);              // duplicates accumulate
    }
    __syncthreads();
    if (t < N_NODES) A[t][t] += dinv[t] * dinv[t];           // self-loop term
    __syncthreads();
    for (int i = t; i < M * AST; i += 128) {
        const int row = i / AST, k = i - row * AST;
        float v = 0.f;
        if (row < N_NODES) { if (k < N_NODES) v = A[row][k]; }
        else if (k >= N_NODES && k < 2 * N_NODES) v = A[row - N_NODES][k - N_NODES];
        const unsigned int u = __float_as_uint(v);
        const unsigned short hi = (unsigned short)(u >> 16);
        const float hf = __uint_as_float(u & 0xFFFF0000u);
        const unsigned short lo = (unsigned short)(__float_as_uint(v - hf) >> 16);
        Ag[i] = hi;
        Ag[M * AST + i] = lo;
    }
}

// ------- W prep: transpose to [c][k] and split fp32 -> bf16 hi/lo planes -------
__global__ __launch_bounds__(256) void k_wprep(
    const float* __restrict__ Wcv, const float* __restrict__ Wr,
    unsigned short* __restrict__ whi, unsigned short* __restrict__ wlo)
{
    int idx = blockIdx.x * 256 + threadIdx.x;    // [0, 5*16384)
    int m = idx >> 14, rem = idx & 16383;
    int k = rem >> 7, c = rem & 127;
    const float* src = (m < 4) ? (Wcv + m * 16384) : Wr;
    float x = src[k * HID + c];
    unsigned int u = __float_as_uint(x);
    unsigned short hi = (unsigned short)(u >> 16);
    float hf = __uint_as_float(u & 0xFFFF0000u);
    unsigned short lo = (unsigned short)(__float_as_uint(x - hf) >> 16);
    whi[m * 16384 + c * HID + k] = hi;
    wlo[m * 16384 + c * HID + k] = lo;
}

__device__ __forceinline__ void split2(float xv, unsigned short& hs, unsigned short& ls)
{
    unsigned int u = __float_as_uint(xv);
    hs = (unsigned short)(u >> 16);
    float hf = __uint_as_float(u & 0xFFFF0000u);
    ls = (unsigned short)(__float_as_uint(xv - hf) >> 16);
}

// ---------------- fully fused GNN: enc + 4x(MFMA conv + MFMA agg) + decoder ----------------
// 512 thr = 8 waves; wave w owns 16 cols (col16=16w+lr), all 48 rows (3 mt tiles).
// Weight residency plan (fits 128-VGPR cap => 4 waves/SIMD):
//   resident: Wch[4]+Wrh[4] hi-planes (32 VGPR) + acc (48) + ahi[3] (12)
//   streamed: Wcl/Wrl lo-planes, one pair per ks, hidden under 12 hi-MFMAs
struct Smem {
    unsigned short planes[2][M * ST];       // h as bf16 hi/lo        (26112 B)
    unsigned short ttT[2][128 * TT + 8];    // t transposed hi/lo     (28704 B); x staged here first
    unsigned short Ap[2][M * AST];          // block-diag A hi/lo     (13824 B)
};                                          // total 68640 B -> 2 blocks/CU

__global__ __launch_bounds__(512, 4) void k_fused(
    const float* __restrict__ x, const float* __restrict__ Wn,
    const float* __restrict__ bn,
    const unsigned short* __restrict__ whi, const unsigned short* __restrict__ wlo,
    const unsigned short* __restrict__ Ag,
    const float* __restrict__ bcv, const float* __restrict__ br,
    const int* __restrict__ ei, const float* __restrict__ ea,
    const float* __restrict__ We, const float* __restrict__ be,
    const float* __restrict__ Wd, const float* __restrict__ bd,
    float* __restrict__ out)
{
    __shared__ Smem s;
    const int t = threadIdx.x;
    const int w = t >> 6, l = t & 63;
    const int lr = l & 15, lq = l >> 4;
    const int col16 = 16 * w + lr;
    const int wko = col16 * HID + 8 * lq;    // weight base offset (add 32*ks)

    // persistent W_res hi fragments (16 VGPR)
    bf16x8 Wrh[4];
#pragma unroll
    for (int ks = 0; ks < 4; ++ks)
        Wrh[ks] = *(const bf16x8*)(whi + 4 * 16384 + wko + 32 * ks);
    const float brc = br[col16];

    // stage x tile (48x16 fp32 = 192 float4) into ttT region + stage Ap
    const long long n0 = (long long)blockIdx.x * M;
    if (t < 192) ((float4*)s.ttT)[t] = ((const float4*)(x + n0 * NODE_F))[t];
    {
        const uint4* src = (const uint4*)Ag;
        uint4* dst = (uint4*)s.Ap;
#pragma unroll 2
        for (int i = t; i < 2 * M * AST / 8; i += 512) dst[i] = src[i];
    }
    __syncthreads();

    // ---- node encoder: h0 = relu(x @ Wn + bn) -> planes ----
    {
        const int c = t & 127, tq = t >> 7;       // tq wave-uniform
        float wn[NODE_F];
#pragma unroll
        for (int k = 0; k < NODE_F; ++k) wn[k] = Wn[k * HID + c];
        const float bnc = bn[c];
        const float* xt = (const float*)s.ttT;     // [48][16]
#pragma unroll
        for (int jj = 0; jj < 12; ++jj) {
            const int n = tq * 12 + jj;
            float acc = bnc;
#pragma unroll
            for (int k = 0; k < NODE_F; ++k) acc = fmaf(xt[n * NODE_F + k], wn[k], acc);
            acc = fmaxf(acc, 0.f);
            unsigned short hs, ls;
            split2(acc, hs, ls);
            s.planes[0][n * ST + c] = hs;
            s.planes[1][n * ST + c] = ls;
        }
    }
    __syncthreads();

    // zero ttT pad regions (k=48..55 per col + tail slop) so MFMA K-overrun reads are finite.
    if (t < 256) {
        *(uint4*)&s.ttT[t >> 7][(t & 127) * TT + 48] = make_uint4(0u, 0u, 0u, 0u);
    } else if (t < 258) {
        *(uint4*)&s.ttT[t - 256][128 * TT] = make_uint4(0u, 0u, 0u, 0u);
    }

    // ---- 4 GCN layers, h resident in LDS; agg via MFMA with block-diag A ----
    for (int lyr = 0; lyr < 4; ++lyr) {
        // conv-W hi fragments for this layer (16 VGPR, L2-hot)
        bf16x8 Wch[4];
#pragma unroll
        for (int ks = 0; ks < 4; ++ks)
            Wch[ks] = *(const bf16x8*)(whi + lyr * 16384 + wko + 32 * ks);
        const float bsum = bcv[lyr * HID + col16] + brc;

        // conv + residual matmuls: accT = h@Wc, accR = h@Wr (3-pass split-bf16).
        // Per ks: issue lo-plane weight loads, run 12 hi-MFMAs (covering load
        // latency), then 6 lo-MFMAs reusing ahi[] kept in registers.
        f32x4 accT[3], accR[3];
#pragma unroll
        for (int mt = 0; mt < 3; ++mt) {
            accT[mt] = (f32x4){0.f, 0.f, 0.f, 0.f};
            accR[mt] = (f32x4){0.f, 0.f, 0.f, 0.f};
        }
#pragma unroll
        for (int ks = 0; ks < 4; ++ks) {
            const int ko = 32 * ks + 8 * lq;
            const bf16x8 Wcl = *(const bf16x8*)(wlo + lyr * 16384 + wko + 32 * ks);
            const bf16x8 Wrl = *(const bf16x8*)(wlo + 4 * 16384 + wko + 32 * ks);
            bf16x8 ahi[3];
#pragma unroll
            for (int mt = 0; mt < 3; ++mt) {
                const int row16 = 16 * mt + lr;
                ahi[mt] = *(const bf16x8*)&s.planes[0][row16 * ST + ko];
                const bf16x8 alo = *(const bf16x8*)&s.planes[1][row16 * ST + ko];
                accT[mt] = __builtin_amdgcn_mfma_f32_16x16x32_bf16(ahi[mt], Wch[ks], accT[mt], 0, 0, 0);
                accT[mt] = __builtin_amdgcn_mfma_f32_16x16x32_bf16(alo, Wch[ks], accT[mt], 0, 0, 0);
                accR[mt] = __builtin_amdgcn_mfma_f32_16x16x32_bf16(ahi[mt], Wrh[ks], accR[mt], 0, 0, 0);
                accR[mt] = __builtin_amdgcn_mfma_f32_16x16x32_bf16(alo, Wrh[ks], accR[mt], 0, 0, 0);
            }
#pragma unroll
            for (int mt = 0; mt < 3; ++mt) {
                accT[mt] = __builtin_amdgcn_mfma_f32_16x16x32_bf16(ahi[mt], Wcl, accT[mt], 0, 0, 0);
                accR[mt] = __builtin_amdgcn_mfma_f32_16x16x32_bf16(ahi[mt], Wrl, accR[mt], 0, 0, 0);
            }
        }

        // write t TRANSPOSED as bf16 hi/lo: ttT[col][k], k = C/D row = 16mt+4lq+j
#pragma unroll
        for (int mt = 0; mt < 3; ++mt) {
            unsigned short hs[4], ls[4];
#pragma unroll
            for (int j = 0; j < 4; ++j) split2(accT[mt][j], hs[j], ls[j]);
            *(ushort4*)&s.ttT[0][col16 * TT + 16 * mt + 4 * lq] = make_ushort4(hs[0], hs[1], hs[2], hs[3]);
            *(ushort4*)&s.ttT[1][col16 * TT + 16 * mt + 4 * lq] = make_ushort4(ls[0], ls[1], ls[2], ls[3]);
        }
        __syncthreads();   // WAR: conv plane-reads done before agg overwrites planes

        // aggregation matmul: accF = Ahi@thi + Alo@thi + Ahi@tlo + accR (C-chained)
        bf16x8 Th[2], Tl[2];
#pragma unroll
        for (int ks = 0; ks < 2; ++ks) {
            Th[ks] = *(const bf16x8*)&s.ttT[0][col16 * TT + 32 * ks + 8 * lq];
            Tl[ks] = *(const bf16x8*)&s.ttT[1][col16 * TT + 32 * ks + 8 * lq];
        }
        f32x4 accF[3];
#pragma unroll
        for (int mt = 0; mt < 3; ++mt) {
            const int arow = (16 * mt + lr) * AST + 8 * lq;
            accF[mt] = accR[mt];
#pragma unroll
            for (int ks = 0; ks < 2; ++ks) {
                const bf16x8 Ah = *(const bf16x8*)&s.Ap[0][arow + 32 * ks];
                const bf16x8 Al = *(const bf16x8*)&s.Ap[1][arow + 32 * ks];
                accF[mt] = __builtin_amdgcn_mfma_f32_16x16x32_bf16(Ah, Th[ks], accF[mt], 0, 0, 0);
                accF[mt] = __builtin_amdgcn_mfma_f32_16x16x32_bf16(Al, Th[ks], accF[mt], 0, 0, 0);
                accF[mt] = __builtin_amdgcn_mfma_f32_16x16x32_bf16(Ah, Tl[ks], accF[mt], 0, 0, 0);
            }
        }

        // bias + relu -> new h planes
#pragma unroll
        for (int mt = 0; mt < 3; ++mt)
#pragma unroll
            for (int j = 0; j < 4; ++j) {
                const int r48 = 16 * mt + 4 * lq + j;
                float v = fmaxf(bsum + accF[mt][j], 0.f);
                unsigned short hs, ls;
                split2(v, hs, ls);
                s.planes[0][r48 * ST + col16] = hs;
                s.planes[1][r48 * ST + col16] = ls;
            }
        __syncthreads();   // RAW: planes complete before next layer's conv reads
    }

    // ---- fused decoder: 152 edges, 19 per wave; h read from planes ----
    {
        const int c0 = l, c1 = l + 64;
        float wef0[8], wef1[8];
#pragma unroll
        for (int f = 0; f < 8; ++f) {
            wef0[f] = We[f * HID + c0];
            wef1[f] = We[f * HID + c1];
        }
        const float wd00 = Wd[c0], wd01 = Wd[c1];
        const float wd10 = Wd[HID + c0], wd11 = Wd[HID + c1];
        const float wd20 = Wd[2 * HID + c0], wd21 = Wd[2 * HID + c1];
        const float be0 = be[c0], be1 = be[c1], bd0 = bd[0];
        for (int it = 0; it < 19; ++it) {
            const int e_loc = 19 * w + it;            // [0,152)
            const int gl = (e_loc >= 76) ? 1 : 0;
            const int j = e_loc - 76 * gl;
            const int g = blockIdx.x * GPB + gl;
            const int e = g * N_EDGES + j;
            const int nrow = ei[e] - g * N_NODES;
            const int ncol = ei[TOT_E + e] - g * N_NODES;
            const float4 a0 = *(const float4*)(ea + (size_t)e * EDGE_F);
            const float4 a1 = *(const float4*)(ea + (size_t)e * EDGE_F + 4);
            float enc0 = be0 + We[(EDGE_F + j) * HID + c0];
            float enc1 = be1 + We[(EDGE_F + j) * HID + c1];
            enc0 = fmaf(a0.x, wef0[0], enc0); enc1 = fmaf(a0.x, wef1[0], enc1);
            enc0 = fmaf(a0.y, wef0[1], enc0); enc1 = fmaf(a0.y, wef1[1], enc1);
            enc0 = fmaf(a0.z, wef0[2], enc0); enc1 = fmaf(a0.z, wef1[2], enc1);
            enc0 = fmaf(a0.w, wef0[3], enc0); enc1 = fmaf(a0.w, wef1[3], enc1);
            enc0 = fmaf(a1.x, wef0[4], enc0); enc1 = fmaf(a1.x, wef1[4], enc1);
            enc0 = fmaf(a1.y, wef0[5], enc0); enc1 = fmaf(a1.y, wef1[5], enc1);
            enc0 = fmaf(a1.z, wef0[6], enc0); enc1 = fmaf(a1.z, wef1[6], enc1);
            enc0 = fmaf(a1.w, wef0[7], enc0); enc1 = fmaf(a1.w, wef1[7], enc1);
            enc0 = fmaxf(enc0, 0.f); enc1 = fmaxf(enc1, 0.f);
            float v = enc0 * wd20 + enc1 * wd21;
            const int rr = gl * N_NODES + nrow, rc = gl * N_NODES + ncol;
            float hr0 = __uint_as_float((unsigned int)s.planes[0][rr * ST + c0] << 16)
                      + __uint_as_float((unsigned int)s.planes[1][rr * ST + c0] << 16);
            float hr1 = __uint_as_float((unsigned int)s.planes[0][rr * ST + c1] << 16)
                      + __uint_as_float((unsigned int)s.planes[1][rr * ST + c1] << 16);
            float hc0 = __uint_as_float((unsigned int)s.planes[0][rc * ST + c0] << 16)
                      + __uint_as_float((unsigned int)s.planes[1][rc * ST + c0] << 16);
            float hc1 = __uint_as_float((unsigned int)s.planes[0][rc * ST + c1] << 16)
                      + __uint_as_float((unsigned int)s.planes[1][rc * ST + c1] << 16);
            v = fmaf(hr0, wd00, v);
            v = fmaf(hr1, wd01, v);
            v = fmaf(hc0, wd10, v);
            v = fmaf(hc1, wd11, v);
#pragma unroll
            for (int o = 32; o > 0; o >>= 1) v += __shfl_xor(v, o, 64);
            if (l == 0) out[e] = v + bd0;
        }
    }
}

extern "C" void kernel_launch(void* const* d_in, const int* in_sizes, int n_in,
                              void* d_out, int out_size, void* d_ws, size_t ws_size,
                              hipStream_t stream) {
    const float* x   = (const float*)d_in[0];
    const int*   ei  = (const int*)d_in[1];   // [2][TOT_E]
    const float* ea  = (const float*)d_in[2];
    /* d_in[3] = batch, unused */
    const float* Wn  = (const float*)d_in[4];
    const float* bn  = (const float*)d_in[5];
    const float* We  = (const float*)d_in[6];
    const float* be  = (const float*)d_in[7];
    const float* Wcv = (const float*)d_in[8];
    const float* bcv = (const float*)d_in[9];
    const float* Wr  = (const float*)d_in[10];
    const float* br  = (const float*)d_in[11];
    const float* Wd  = (const float*)d_in[12];
    const float* bd  = (const float*)d_in[13];
    float* out = (float*)d_out;

    char* ws = (char*)d_ws;
    unsigned short* whi = (unsigned short*)ws;                // 5*16384 bf16
    unsigned short* wlo = whi + 5 * 16384;
    unsigned short* Ag  = wlo + 5 * 16384;                    // 2*48*72 bf16

    k_pattern<<<1, 128, 0, stream>>>(ei, Ag);
    k_wprep<<<5 * 16384 / 256, 256, 0, stream>>>(Wcv, Wr, whi, wlo);
    k_fused<<<N_GRAPHS / GPB, 512, 0, stream>>>(x, Wn, bn, whi, wlo, Ag, bcv, br,
                                                ei, ea, We, be, Wd, bd, out);
}

// Round 8
// 321.572 us; speedup vs baseline: 7.8997x; 1.0110x over previous
//
#include <hip/hip_runtime.h>

typedef short bf16x8 __attribute__((ext_vector_type(8)));
typedef float f32x4  __attribute__((ext_vector_type(4)));

#define N_NODES 24
#define N_EDGES 76
#define N_GRAPHS 8192
#define HID 128
#define NODE_F 16
#define EDGE_F 8
#define TOT_E (N_EDGES * N_GRAPHS)   /* 622592 */
#define ST 136     /* bf16 h-plane stride (ushorts) */
#define TT 56      /* ttT (t transposed) stride in ushorts */
#define AST 72     /* Ap (block-diag adjacency) stride in ushorts */
#define GPB 2      /* graphs per block */
#define M 48       /* rows per block = GPB*24 */

// ------- static normalized adjacency (identical topology across graphs) -------
__global__ void k_pattern(const int* __restrict__ ei, unsigned short* __restrict__ Ag)
{
    __shared__ float A[N_NODES][N_NODES];
    __shared__ int cnt[N_NODES];
    __shared__ float dinv[N_NODES];
    const int t = threadIdx.x;   // 128 threads
    for (int i = t; i < N_NODES * N_NODES; i += 128) ((float*)A)[i] = 0.f;
    if (t < N_NODES) cnt[t] = 0;
    __syncthreads();
    if (t < N_EDGES) atomicAdd(&cnt[ei[TOT_E + t]], 1);   // in-degree by col
    __syncthreads();
    if (t < N_NODES) dinv[t] = rsqrtf((float)(cnt[t] + 1));  // +1 self loop
    __syncthreads();
    if (t < N_EDGES) {
        const int r = ei[t], c = ei[TOT_E + t];              // graph-0 ids are local
        atomicAdd(&A[c][r], dinv[r] * dinv[c]);              // duplicates accumulate
    }
    __syncthreads();
    if (t < N_NODES) A[t][t] += dinv[t] * dinv[t];           // self-loop term
    __syncthreads();
    for (int i = t; i < M * AST; i += 128) {
        const int row = i / AST, k = i - row * AST;
        float v = 0.f;
        if (row < N_NODES) { if (k < N_NODES) v = A[row][k]; }
        else if (k >= N_NODES && k < 2 * N_NODES) v = A[row - N_NODES][k - N_NODES];
        const unsigned int u = __float_as_uint(v);
        const unsigned short hi = (unsigned short)(u >> 16);
        const float hf = __uint_as_float(u & 0xFFFF0000u);
        const unsigned short lo = (unsigned short)(__float_as_uint(v - hf) >> 16);
        Ag[i] = hi;
        Ag[M * AST + i] = lo;
    }
}

// ------- W prep: transpose to [c][k] and split fp32 -> bf16 hi/lo planes -------
__global__ __launch_bounds__(256) void k_wprep(
    const float* __restrict__ Wcv, const float* __restrict__ Wr,
    unsigned short* __restrict__ whi, unsigned short* __restrict__ wlo)
{
    int idx = blockIdx.x * 256 + threadIdx.x;    // [0, 5*16384)
    int m = idx >> 14, rem = idx & 16383;
    int k = rem >> 7, c = rem & 127;
    const float* src = (m < 4) ? (Wcv + m * 16384) : Wr;
    float x = src[k * HID + c];
    unsigned int u = __float_as_uint(x);
    unsigned short hi = (unsigned short)(u >> 16);
    float hf = __uint_as_float(u & 0xFFFF0000u);
    unsigned short lo = (unsigned short)(__float_as_uint(x - hf) >> 16);
    whi[m * 16384 + c * HID + k] = hi;
    wlo[m * 16384 + c * HID + k] = lo;
}

__device__ __forceinline__ void split2(float xv, unsigned short& hs, unsigned short& ls)
{
    unsigned int u = __float_as_uint(xv);
    hs = (unsigned short)(u >> 16);
    float hf = __uint_as_float(u & 0xFFFF0000u);
    ls = (unsigned short)(__float_as_uint(xv - hf) >> 16);
}

// ---------------- fully fused GNN: enc + 4x(MFMA conv + MFMA agg^T) + decoder ----------------
// 512 thr = 8 waves; wave w owns 16 cols (col16=16w+lr), all 48 rows (3 tiles).
// conv computed standard (D[node][hcol]); residual+agg computed TRANSPOSED via
// operand swap (D[hcol][node]) so the h-plane writeback is 4 consecutive hcols
// per thread -> b64 stores (kills the b16-scatter bank conflicts of R7).
struct Smem {
    unsigned short planes[2][M * ST];       // h as bf16 hi/lo        (26112 B)
    unsigned short ttT[2][128 * TT + 8];    // t transposed hi/lo     (28704 B); x staged here first
    unsigned short Ap[2][M * AST];          // block-diag A hi/lo     (13824 B)
};                                          // total 68640 B -> 2 blocks/CU

__global__ __launch_bounds__(512, 4) void k_fused(
    const float* __restrict__ x, const float* __restrict__ Wn,
    const float* __restrict__ bn,
    const unsigned short* __restrict__ whi, const unsigned short* __restrict__ wlo,
    const unsigned short* __restrict__ Ag,
    const float* __restrict__ bcv, const float* __restrict__ br,
    const int* __restrict__ ei, const float* __restrict__ ea,
    const float* __restrict__ We, const float* __restrict__ be,
    const float* __restrict__ Wd, const float* __restrict__ bd,
    float* __restrict__ out)
{
    __shared__ Smem s;
    const int t = threadIdx.x;
    const int w = t >> 6, l = t & 63;
    const int lr = l & 15, lq = l >> 4;
    const int col16 = 16 * w + lr;
    const int hcb = 16 * w + 4 * lq;         // hcol base for transposed C/D rows
    const int wko = col16 * HID + 8 * lq;    // weight base offset (add 32*ks)

    // persistent W_res hi fragments (16 VGPR)
    bf16x8 Wrh[4];
#pragma unroll
    for (int ks = 0; ks < 4; ++ks)
        Wrh[ks] = *(const bf16x8*)(whi + 4 * 16384 + wko + 32 * ks);
    const float4 br4 = *(const float4*)(br + hcb);

    // stage x tile (48x16 fp32 = 192 float4) into ttT region + stage Ap
    const long long n0 = (long long)blockIdx.x * M;
    if (t < 192) ((float4*)s.ttT)[t] = ((const float4*)(x + n0 * NODE_F))[t];
    {
        const uint4* src = (const uint4*)Ag;
        uint4* dst = (uint4*)s.Ap;
#pragma unroll 2
        for (int i = t; i < 2 * M * AST / 8; i += 512) dst[i] = src[i];
    }
    __syncthreads();

    // ---- node encoder: h0 = relu(x @ Wn + bn) -> planes ----
    {
        const int c = t & 127, tq = t >> 7;       // tq wave-uniform
        float wn[NODE_F];
#pragma unroll
        for (int k = 0; k < NODE_F; ++k) wn[k] = Wn[k * HID + c];
        const float bnc = bn[c];
        const float* xt = (const float*)s.ttT;     // [48][16]
#pragma unroll
        for (int jj = 0; jj < 12; ++jj) {
            const int n = tq * 12 + jj;
            float acc = bnc;
#pragma unroll
            for (int k = 0; k < NODE_F; ++k) acc = fmaf(xt[n * NODE_F + k], wn[k], acc);
            acc = fmaxf(acc, 0.f);
            unsigned short hs, ls;
            split2(acc, hs, ls);
            s.planes[0][n * ST + c] = hs;
            s.planes[1][n * ST + c] = ls;
        }
    }
    __syncthreads();

    // zero ttT pad regions (k=48..55 per col + tail slop): keeps any K-overrun finite.
    if (t < 256) {
        *(uint4*)&s.ttT[t >> 7][(t & 127) * TT + 48] = make_uint4(0u, 0u, 0u, 0u);
    } else if (t < 258) {
        *(uint4*)&s.ttT[t - 256][128 * TT] = make_uint4(0u, 0u, 0u, 0u);
    }

    // ---- 4 GCN layers, h resident in LDS ----
    for (int lyr = 0; lyr < 4; ++lyr) {
        // conv-W hi fragments for this layer (16 VGPR, L2-hot)
        bf16x8 Wch[4];
#pragma unroll
        for (int ks = 0; ks < 4; ++ks)
            Wch[ks] = *(const bf16x8*)(whi + lyr * 16384 + wko + 32 * ks);
        const float4 bc4 = *(const float4*)(bcv + lyr * HID + hcb);

        // conv (standard): accT[mt] = (h@Wc)[node][hcol]
        // residual (TRANSPOSED, operand swap): accRT[nt] = (h@Wr)^T[hcol][node]
        f32x4 accT[3], accRT[3];
#pragma unroll
        for (int mt = 0; mt < 3; ++mt) {
            accT[mt]  = (f32x4){0.f, 0.f, 0.f, 0.f};
            accRT[mt] = (f32x4){0.f, 0.f, 0.f, 0.f};
        }
#pragma unroll
        for (int ks = 0; ks < 4; ++ks) {
            const int ko = 32 * ks + 8 * lq;
            const bf16x8 Wcl = *(const bf16x8*)(wlo + lyr * 16384 + wko + 32 * ks);
            const bf16x8 Wrl = *(const bf16x8*)(wlo + 4 * 16384 + wko + 32 * ks);
            bf16x8 ahi[3];
#pragma unroll
            for (int mt = 0; mt < 3; ++mt) {
                const int row16 = 16 * mt + lr;
                ahi[mt] = *(const bf16x8*)&s.planes[0][row16 * ST + ko];
                const bf16x8 alo = *(const bf16x8*)&s.planes[1][row16 * ST + ko];
                accT[mt]  = __builtin_amdgcn_mfma_f32_16x16x32_bf16(ahi[mt], Wch[ks], accT[mt], 0, 0, 0);
                accT[mt]  = __builtin_amdgcn_mfma_f32_16x16x32_bf16(alo, Wch[ks], accT[mt], 0, 0, 0);
                accRT[mt] = __builtin_amdgcn_mfma_f32_16x16x32_bf16(Wrh[ks], ahi[mt], accRT[mt], 0, 0, 0);
                accRT[mt] = __builtin_amdgcn_mfma_f32_16x16x32_bf16(Wrh[ks], alo, accRT[mt], 0, 0, 0);
            }
#pragma unroll
            for (int mt = 0; mt < 3; ++mt) {
                accT[mt]  = __builtin_amdgcn_mfma_f32_16x16x32_bf16(ahi[mt], Wcl, accT[mt], 0, 0, 0);
                accRT[mt] = __builtin_amdgcn_mfma_f32_16x16x32_bf16(Wrl, ahi[mt], accRT[mt], 0, 0, 0);
            }
        }

        // write t TRANSPOSED as bf16 hi/lo: ttT[col][k], k = C/D row = 16mt+4lq+j
#pragma unroll
        for (int mt = 0; mt < 3; ++mt) {
            unsigned short hs[4], ls[4];
#pragma unroll
            for (int j = 0; j < 4; ++j) split2(accT[mt][j], hs[j], ls[j]);
            *(ushort4*)&s.ttT[0][col16 * TT + 16 * mt + 4 * lq] = make_ushort4(hs[0], hs[1], hs[2], hs[3]);
            *(ushort4*)&s.ttT[1][col16 * TT + 16 * mt + 4 * lq] = make_ushort4(ls[0], ls[1], ls[2], ls[3]);
        }
        __syncthreads();   // WAR: conv plane-reads done before agg overwrites planes

        // aggregation TRANSPOSED: accF[nt] = (A@t)^T[hcol][node] + accRT[nt]
        //   A-operand = t^T fragments (same ttT reads), B-operand = Ap fragments
        bf16x8 Th[2], Tl[2];
#pragma unroll
        for (int ks = 0; ks < 2; ++ks) {
            Th[ks] = *(const bf16x8*)&s.ttT[0][col16 * TT + 32 * ks + 8 * lq];
            Tl[ks] = *(const bf16x8*)&s.ttT[1][col16 * TT + 32 * ks + 8 * lq];
        }
        f32x4 accF[3];
#pragma unroll
        for (int nt = 0; nt < 3; ++nt) {
            const int brow = (16 * nt + lr) * AST + 8 * lq;
            accF[nt] = accRT[nt];
#pragma unroll
            for (int ks = 0; ks < 2; ++ks) {
                const bf16x8 Bh = *(const bf16x8*)&s.Ap[0][brow + 32 * ks];
                const bf16x8 Bl = *(const bf16x8*)&s.Ap[1][brow + 32 * ks];
                accF[nt] = __builtin_amdgcn_mfma_f32_16x16x32_bf16(Th[ks], Bh, accF[nt], 0, 0, 0);
                accF[nt] = __builtin_amdgcn_mfma_f32_16x16x32_bf16(Tl[ks], Bh, accF[nt], 0, 0, 0);
                accF[nt] = __builtin_amdgcn_mfma_f32_16x16x32_bf16(Th[ks], Bl, accF[nt], 0, 0, 0);
            }
        }

        // bias + relu -> new h planes. Thread holds node=16nt+lr, hcols hcb..hcb+3
        // -> contiguous ushort4 (b64) stores, conflict-free (2-way max).
#pragma unroll
        for (int nt = 0; nt < 3; ++nt) {
            const int node = 16 * nt + lr;
            unsigned short hs[4], ls[4];
            const float bb[4] = {bc4.x + br4.x, bc4.y + br4.y, bc4.z + br4.z, bc4.w + br4.w};
#pragma unroll
            for (int j = 0; j < 4; ++j) {
                float v = fmaxf(accF[nt][j] + bb[j], 0.f);
                split2(v, hs[j], ls[j]);
            }
            *(ushort4*)&s.planes[0][node * ST + hcb] = make_ushort4(hs[0], hs[1], hs[2], hs[3]);
            *(ushort4*)&s.planes[1][node * ST + hcb] = make_ushort4(ls[0], ls[1], ls[2], ls[3]);
        }
        __syncthreads();   // RAW: planes complete before next layer's conv reads
    }

    // ---- fused decoder: 152 edges, 19 per wave; h read from planes ----
    {
        const int c0 = l, c1 = l + 64;
        float wef0[8], wef1[8];
#pragma unroll
        for (int f = 0; f < 8; ++f) {
            wef0[f] = We[f * HID + c0];
            wef1[f] = We[f * HID + c1];
        }
        const float wd00 = Wd[c0], wd01 = Wd[c1];
        const float wd10 = Wd[HID + c0], wd11 = Wd[HID + c1];
        const float wd20 = Wd[2 * HID + c0], wd21 = Wd[2 * HID + c1];
        const float be0 = be[c0], be1 = be[c1], bd0 = bd[0];
        for (int it = 0; it < 19; ++it) {
            const int e_loc = 19 * w + it;            // [0,152)
            const int gl = (e_loc >= 76) ? 1 : 0;
            const int j = e_loc - 76 * gl;
            const int g = blockIdx.x * GPB + gl;
            const int e = g * N_EDGES + j;
            const int nrow = ei[e] - g * N_NODES;
            const int ncol = ei[TOT_E + e] - g * N_NODES;
            const float4 a0 = *(const float4*)(ea + (size_t)e * EDGE_F);
            const float4 a1 = *(const float4*)(ea + (size_t)e * EDGE_F + 4);
            float enc0 = be0 + We[(EDGE_F + j) * HID + c0];
            float enc1 = be1 + We[(EDGE_F + j) * HID + c1];
            enc0 = fmaf(a0.x, wef0[0], enc0); enc1 = fmaf(a0.x, wef1[0], enc1);
            enc0 = fmaf(a0.y, wef0[1], enc0); enc1 = fmaf(a0.y, wef1[1], enc1);
            enc0 = fmaf(a0.z, wef0[2], enc0); enc1 = fmaf(a0.z, wef1[2], enc1);
            enc0 = fmaf(a0.w, wef0[3], enc0); enc1 = fmaf(a0.w, wef1[3], enc1);
            enc0 = fmaf(a1.x, wef0[4], enc0); enc1 = fmaf(a1.x, wef1[4], enc1);
            enc0 = fmaf(a1.y, wef0[5], enc0); enc1 = fmaf(a1.y, wef1[5], enc1);
            enc0 = fmaf(a1.z, wef0[6], enc0); enc1 = fmaf(a1.z, wef1[6], enc1);
            enc0 = fmaf(a1.w, wef0[7], enc0); enc1 = fmaf(a1.w, wef1[7], enc1);
            enc0 = fmaxf(enc0, 0.f); enc1 = fmaxf(enc1, 0.f);
            float v = enc0 * wd20 + enc1 * wd21;
            const int rr = gl * N_NODES + nrow, rc = gl * N_NODES + ncol;
            float hr0 = __uint_as_float((unsigned int)s.planes[0][rr * ST + c0] << 16)
                      + __uint_as_float((unsigned int)s.planes[1][rr * ST + c0] << 16);
            float hr1 = __uint_as_float((unsigned int)s.planes[0][rr * ST + c1] << 16)
                      + __uint_as_float((unsigned int)s.planes[1][rr * ST + c1] << 16);
            float hc0 = __uint_as_float((unsigned int)s.planes[0][rc * ST + c0] << 16)
                      + __uint_as_float((unsigned int)s.planes[1][rc * ST + c0] << 16);
            float hc1 = __uint_as_float((unsigned int)s.planes[0][rc * ST + c1] << 16)
                      + __uint_as_float((unsigned int)s.planes[1][rc * ST + c1] << 16);
            v = fmaf(hr0, wd00, v);
            v = fmaf(hr1, wd01, v);
            v = fmaf(hc0, wd10, v);
            v = fmaf(hc1, wd11, v);
#pragma unroll
            for (int o = 32; o > 0; o >>= 1) v += __shfl_xor(v, o, 64);
            if (l == 0) out[e] = v + bd0;
        }
    }
}

extern "C" void kernel_launch(void* const* d_in, const int* in_sizes, int n_in,
                              void* d_out, int out_size, void* d_ws, size_t ws_size,
                              hipStream_t stream) {
    const float* x   = (const float*)d_in[0];
    const int*   ei  = (const int*)d_in[1];   // [2][TOT_E]
    const float* ea  = (const float*)d_in[2];
    /* d_in[3] = batch, unused */
    const float* Wn  = (const float*)d_in[4];
    const float* bn  = (const float*)d_in[5];
    const float* We  = (const float*)d_in[6];
    const float* be  = (const float*)d_in[7];
    const float* Wcv = (const float*)d_in[8];
    const float* bcv = (const float*)d_in[9];
    const float* Wr  = (const float*)d_in[10];
    const float* br  = (const float*)d_in[11];
    const float* Wd  = (const float*)d_in[12];
    const float* bd  = (const float*)d_in[13];
    float* out = (float*)d_out;

    char* ws = (char*)d_ws;
    unsigned short* whi = (unsigned short*)ws;                // 5*16384 bf16
    unsigned short* wlo = whi + 5 * 16384;
    unsigned short* Ag  = wlo + 5 * 16384;                    // 2*48*72 bf16

    k_pattern<<<1, 128, 0, stream>>>(ei, Ag);
    k_wprep<<<5 * 16384 / 256, 256, 0, stream>>>(Wcv, Wr, whi, wlo);
    k_fused<<<N_GRAPHS / GPB, 512, 0, stream>>>(x, Wn, bn, whi, wlo, Ag, bcv, br,
                                                ei, ea, We, be, Wd, bd, out);
}